// Round 9
// baseline (436.796 us; speedup 1.0000x reference)
//
#include <hip/hip_runtime.h>
#include <hip/hip_bf16.h>
#include <math.h>

#define N_NODES 50000
#define N_EDGES 640000
#define EPAD (N_EDGES + 4 * N_NODES)   // CSR padded to multiples of 4 per node
#define DIM 128
#define NLAYER 3
#define LN_EPS 1e-5f
#define LOG2E 1.44269504088896f
#define NSCAN 49   // ceil(50000/1024)

#if __has_builtin(__builtin_amdgcn_exp2f)
#define EXP2(x) __builtin_amdgcn_exp2f(x)
#else
#define EXP2(x) exp2f(x)
#endif

typedef __attribute__((ext_vector_type(8))) short bf16x8;
typedef __attribute__((ext_vector_type(4))) float f32x4;

__device__ inline ushort f2b(float f) {
    __hip_bfloat16 h = __float2bfloat16(f);
    return *reinterpret_cast<ushort*>(&h);
}
__device__ inline float bf_lo(unsigned u) { return __uint_as_float(u << 16); }
__device__ inline float bf_hi(unsigned u) { return __uint_as_float(u & 0xffff0000u); }
// leaky_relu(t) = 0.6t + 0.4|t|  (NEG_SLOPE=0.2)
__device__ inline float lr(float t) { return fmaf(0.4f, fabsf(t), 0.6f * t); }
__device__ inline unsigned pack2(float a, float b) {
    return (unsigned)f2b(a) | ((unsigned)f2b(b) << 16);
}
// packed word w of a node row holds channels (cw, cw+16); head = w>>4.
__device__ inline int cw_of(int w) { return (w & 15) + 32 * (w >> 4); }

// DPP-based add of cross-lane neighbor (VALU, no LDS pipe).
template<int CTRL>
__device__ inline float dppadd(float v) {
    int m = __builtin_amdgcn_update_dpp(0, __float_as_int(v), CTRL, 0xF, 0xF, true);
    return v + __int_as_float(m);
}
// sum over each 16-lane group
__device__ inline float reduce16(float v) {
    v = dppadd<0x124>(v);   // row_ror:4
    v = dppadd<0x128>(v);   // row_ror:8
    v = dppadd<0xB1>(v);    // quad_perm [1,0,3,2]
    v = dppadd<0x4E>(v);    // quad_perm [2,3,0,1]
    return v;
}

// ---------------- zero-fill (zbase + esrc pads, contiguous region) ----------------

__global__ __launch_bounds__(256) void zerofill(int4* __restrict__ p, int n4) {
    int i = blockIdx.x * 256 + threadIdx.x;
    if (i < n4) p[i] = make_int4(0, 0, 0, 0);
}

// ---------------- fused init: curb pack + Wt convert(k-perm) + deg hist + params ----

__global__ __launch_bounds__(256) void fusedinit(
    const float* __restrict__ x, unsigned* __restrict__ curb,
    const float* __restrict__ Wl, const float* __restrict__ Wr, ushort* __restrict__ Wt,
    const int* __restrict__ dst, int* __restrict__ deg,
    const float* __restrict__ att, const float* __restrict__ bias,
    const float* __restrict__ gamma, const float* __restrict__ beta,
    float2* __restrict__ params)
{
    int b = blockIdx.x, t = threadIdx.x;
    if (b < 12500) {
        int i = b * 256 + t;                 // i < N*64
        int node = i >> 6, w = i & 63;
        int c = cw_of(w);
        curb[i] = pack2(x[node * DIM + c], x[node * DIM + c + 16]);
    } else if (b < 12884) {
        int i = (b - 12500) * 256 + t;
        if (i < NLAYER * 2 * DIM * DIM) {
            int p = i & 127, n = (i >> 7) & 127, mat = (i >> 14) & 1, l = i >> 15;
            int c = cw_of(p >> 1) + (p & 1) * 16;
            const float* W = mat ? Wr : Wl;
            Wt[i] = f2b(W[l * DIM * DIM + c * DIM + n]);
        }
    } else if (b < 15384) {
        int e = (b - 12884) * 256 + t;       // e < 640000 exactly
        atomicAdd(&deg[dst[e]], 1);
    } else {
        int i = t;
        if (i < NLAYER * 64) {
            int l = i >> 6, w = i & 63;
            int c = cw_of(w);
            const float* A = att + l * DIM;
            const float* B = bias + l * DIM;
            const float* G = gamma + l * DIM;
            const float* E = beta + l * DIM;
            params[l * 256 + w]       = make_float2(A[c] * LOG2E, A[c + 16] * LOG2E);
            params[l * 256 + 64 + w]  = make_float2(B[c], B[c + 16]);
            params[l * 256 + 128 + w] = make_float2(G[c], G[c + 16]);
            params[l * 256 + 192 + w] = make_float2(E[c], E[c + 16]);
        }
    }
}

// ---------------- CSR build (padded to x4) + contention-free counting sort ----------

__global__ __launch_bounds__(1024) void scan1(const int* __restrict__ deg,
                                              int* __restrict__ rowptr,
                                              int* __restrict__ bsum,
                                              int* __restrict__ blockhist) {
    __shared__ int sd[1024];
    __shared__ int lh[256];
    int t = threadIdx.x;
    int idx = blockIdx.x * 1024 + t;
    if (t < 256) lh[t] = 0;
    __syncthreads();
    int v = (idx < N_NODES) ? deg[idx] : 0;
    if (idx < N_NODES) atomicAdd(&lh[v < 255 ? v : 255], 1);
    sd[t] = (v + 3) & ~3;                 // padded degree for CSR slots
    __syncthreads();
    for (int off = 1; off < 1024; off <<= 1) {
        int add = (t >= off) ? sd[t - off] : 0;
        __syncthreads();
        sd[t] += add;
        __syncthreads();
    }
    if (idx < N_NODES) rowptr[idx + 1] = sd[t];
    if (t == 1023) bsum[blockIdx.x] = sd[1023];
    if (t < 256) blockhist[blockIdx.x * 256 + t] = lh[t];
}

__global__ __launch_bounds__(1024) void midscan(const int* __restrict__ bsum,
                                                int* __restrict__ bcarry,
                                                const int* __restrict__ blockhist,
                                                int* __restrict__ bboff) {
    __shared__ int sh[256];
    int t = threadIdx.x;
    if (t < 256) {
        int tot = 0;
        for (int b = 0; b < NSCAN; ++b) tot += blockhist[b * 256 + t];
        sh[t] = tot;
    }
    __syncthreads();
    for (int off = 1; off < 256; off <<= 1) {
        int add = 0;
        if (t < 256 && t >= off) add = sh[t - off];
        __syncthreads();
        if (t < 256) sh[t] += add;
        __syncthreads();
    }
    if (t < 256) {
        int run = sh[255] - sh[t];          // heavy-first
        for (int b = 0; b < NSCAN; ++b) {
            bboff[b * 256 + t] = run;
            run += blockhist[b * 256 + t];
        }
    }
    if (t == 0) {
        int c = 0;
        for (int b = 0; b < NSCAN; ++b) { bcarry[b] = c; c += bsum[b]; }
    }
}

__global__ __launch_bounds__(1024) void scan2(int* __restrict__ rowptr,
                                              const int* __restrict__ bcarry,
                                              const int* __restrict__ deg,
                                              const int* __restrict__ bboff,
                                              int* __restrict__ order) {
    __shared__ int lh[256];
    int t = threadIdx.x;
    int idx = blockIdx.x * 1024 + t;
    if (t < 256) lh[t] = 0;
    __syncthreads();
    int carry = bcarry[blockIdx.x];
    if (idx == 0) rowptr[0] = 0;
    if (idx < N_NODES) {
        rowptr[idx + 1] += carry;
        int d = deg[idx];
        int bin = d < 255 ? d : 255;
        int rank = atomicAdd(&lh[bin], 1);
        order[bboff[blockIdx.x * 256 + bin] + rank] = idx;
    }
}

// esrc holds BYTE offsets (src*64) into head-sliced rows; pads stay 0 (masked).
__global__ void scatter_kernel(const int* __restrict__ src, const int* __restrict__ dst,
                               const int* __restrict__ rowptr, int* __restrict__ cnt,
                               int* __restrict__ esrc) {
    int e = blockIdx.x * blockDim.x + threadIdx.x;
    if (e < N_EDGES) {
        int d = dst[e];
        int pos = rowptr[d] + atomicAdd(&cnt[d], 1);
        esrc[pos] = src[e] << 6;
    }
}

// ---------------- MFMA GEMM: head-major packed output [4][N][16] ----------------

__global__ __launch_bounds__(256) void gemm_mfma(
    const ushort* __restrict__ A,      // [N][128] bf16, k-permuted packed order
    const ushort* __restrict__ Wt_l,   // [2][128n][128kperm] bf16
    const float* __restrict__ bl, const float* __restrict__ br,
    unsigned* __restrict__ xlh, unsigned* __restrict__ xrh)
{
    int mat = blockIdx.y;
    int rowbase = blockIdx.x * 128;
    int wid = threadIdx.x >> 6;
    int lane = threadIdx.x & 63;
    int wr = wid >> 1, wc = wid & 1;
    int m0 = rowbase + wr * 64, n0 = wc * 64;

    const ushort* W = Wt_l + mat * DIM * DIM;
    const float* bias = mat ? br : bl;
    unsigned* out = mat ? xrh : xlh;

    int fr = lane & 15;
    int kg = lane >> 4;

    bf16x8 af[4][4], bfr[4][4];
    #pragma unroll
    for (int mf = 0; mf < 4; ++mf) {
        int row = m0 + mf * 16 + fr;
        if (row > N_NODES - 1) row = N_NODES - 1;
        const ushort* p = A + (size_t)row * DIM + kg * 8;
        #pragma unroll
        for (int kf = 0; kf < 4; ++kf)
            af[mf][kf] = *reinterpret_cast<const bf16x8*>(p + kf * 32);
    }
    #pragma unroll
    for (int nf = 0; nf < 4; ++nf) {
        const ushort* p = W + (size_t)(n0 + nf * 16 + fr) * DIM + kg * 8;
        #pragma unroll
        for (int kf = 0; kf < 4; ++kf)
            bfr[nf][kf] = *reinterpret_cast<const bf16x8*>(p + kf * 32);
    }

    f32x4 acc[4][4];
    #pragma unroll
    for (int mf = 0; mf < 4; ++mf)
        #pragma unroll
        for (int nf = 0; nf < 4; ++nf)
            acc[mf][nf] = (f32x4){0.f, 0.f, 0.f, 0.f};

    #pragma unroll
    for (int kf = 0; kf < 4; ++kf)
        #pragma unroll
        for (int mf = 0; mf < 4; ++mf)
            #pragma unroll
            for (int nf = 0; nf < 4; ++nf)
                acc[mf][nf] = __builtin_amdgcn_mfma_f32_16x16x32_bf16(
                    af[mf][kf], bfr[nf][kf], acc[mf][nf], 0, 0, 0);

    int col = lane & 15;
    int r4 = lane >> 4;
    float bb[4];
    #pragma unroll
    for (int nf = 0; nf < 4; ++nf) bb[nf] = bias[n0 + nf * 16 + col];

    #pragma unroll
    for (int mf = 0; mf < 4; ++mf) {
        #pragma unroll
        for (int pj = 0; pj < 2; ++pj) {
            // pair channels c=64wc+32pj+col, c+16 -> head h=2wc+pj, word ww=col
            int h = 2 * wc + pj;
            #pragma unroll
            for (int r = 0; r < 4; ++r) {
                int row = m0 + mf * 16 + r4 * 4 + r;
                if (row < N_NODES)
                    out[((size_t)(h * N_NODES + row) << 4) + col] =
                        pack2(acc[mf][2 * pj][r] + bb[2 * pj],
                              acc[mf][2 * pj + 1][r] + bb[2 * pj + 1]);
            }
        }
    }
}

// ---------------- per-head aggregation: wave = (node, head), 4 edges/iter --------
// L2-locality: head = blockIdx&3 -> XCDs {h, h+4} serve one 3.2MB slice.

__global__ __launch_bounds__(256) void agg_head(
    const unsigned* __restrict__ xlh, const unsigned* __restrict__ xrh,
    const int* __restrict__ esrc, const int* __restrict__ prow,
    const int* __restrict__ deg, const int* __restrict__ order,
    const float2* __restrict__ P4, unsigned* __restrict__ aggh)
{
    int bid = blockIdx.x;
    int h = bid & 3;
    int slot = ((bid >> 2) << 2) + (threadIdx.x >> 6);
    int lane = threadIdx.x & 63;
    int ww = lane & 15;     // word within head slice (channels ww, ww+16 of head)
    int q  = lane >> 4;     // edge slot 0..3
    int node = __builtin_amdgcn_readfirstlane(order[slot]);

    float2 att2 = P4[(h << 4) | ww];
    unsigned xru = xrh[((size_t)(h * N_NODES + node) << 4) + ww];
    float xrx = bf_lo(xru), xry = bf_hi(xru);
    const char* xb = (const char*)xlh + (size_t)h * N_NODES * 64;
    int laneoff = ww << 2;

    float s = 0.f, ox = 0.f, oy = 0.f;
    int e0 = prow[node];        // multiple of 4
    int dt = deg[node];
    int nit = (dt + 3) >> 2;

    #pragma unroll 2
    for (int it = 0; it < nit; ++it) {
        int e = e0 + it * 4;
        int4 jj = *reinterpret_cast<const int4*>(esrc + e);   // uniform -> s_load_dwordx4
        int j = q == 0 ? jj.x : q == 1 ? jj.y : q == 2 ? jj.z : jj.w;
        unsigned u = *(const unsigned*)(xb + j + laneoff);
        float vx = bf_lo(u), vy = bf_hi(u);
        float p = fmaf(lr(vy + xry), att2.y, lr(vx + xrx) * att2.x);
        p = reduce16(p);
        int rem = dt - it * 4;                     // uniform
        float w = (q < rem) ? EXP2(p) : 0.f;       // mask pad edges
        s += w; ox = fmaf(w, vx, ox); oy = fmaf(w, vy, oy);
    }
    // fold the 4 edge-slot groups
    s  += __shfl_xor(s, 16);  s  += __shfl_xor(s, 32);
    ox += __shfl_xor(ox, 16); ox += __shfl_xor(ox, 32);
    oy += __shfl_xor(oy, 16); oy += __shfl_xor(oy, 32);
    float inv = 1.f / (s + 1e-16f);
    if (lane < 16)
        aggh[((size_t)(h * N_NODES + node) << 4) + ww] = pack2(ox * inv, oy * inv);
}

// ---------------- bias + relu + LayerNorm + residual (streaming) ----------------

__global__ __launch_bounds__(256) void ln_res(
    const unsigned* __restrict__ aggh, const float2* __restrict__ P4,
    unsigned* __restrict__ curb, float* __restrict__ outf, int last)
{
    int node = blockIdx.x * 4 + (threadIdx.x >> 6);
    int lane = threadIdx.x & 63;
    int h = lane >> 4, ww = lane & 15;
    unsigned u = aggh[((size_t)(h * N_NODES + node) << 4) + ww];
    float ox = bf_lo(u), oy = bf_hi(u);

    float2 b2 = P4[64 + lane];
    float gx = fmaxf(ox + b2.x, 0.f);
    float gy = fmaxf(oy + b2.y, 0.f);

    float sum = gx + gy;
    sum = reduce16(sum);
    sum += __shfl_xor(sum, 16);
    sum += __shfl_xor(sum, 32);
    float mu = sum * (1.f / 128.f);
    float dx = gx - mu, dy = gy - mu;
    float ss = dx * dx + dy * dy;
    ss = reduce16(ss);
    ss += __shfl_xor(ss, 16);
    ss += __shfl_xor(ss, 32);
    float rstd = rsqrtf(ss * (1.f / 128.f) + LN_EPS);

    float2 g2  = P4[128 + lane];
    float2 be2 = P4[192 + lane];
    unsigned old = curb[node * 64 + lane];
    float yx = fmaf(dx * rstd, g2.x, be2.x) + bf_lo(old);
    float yy = fmaf(dy * rstd, g2.y, be2.y) + bf_hi(old);

    if (last) {
        int c = cw_of(lane);
        outf[node * DIM + c] = yx;
        outf[node * DIM + c + 16] = yy;
    } else {
        curb[node * 64 + lane] = pack2(yx, yy);
    }
}

// ---------------- launch ----------------

extern "C" void kernel_launch(void* const* d_in, const int* in_sizes, int n_in,
                              void* d_out, int out_size, void* d_ws, size_t ws_size,
                              hipStream_t stream) {
    const float* x     = (const float*)d_in[0];
    const int*   ei    = (const int*)d_in[1];
    const float* Wl    = (const float*)d_in[2];
    const float* bl    = (const float*)d_in[3];
    const float* Wr    = (const float*)d_in[4];
    const float* br    = (const float*)d_in[5];
    const float* att   = (const float*)d_in[6];
    const float* bias  = (const float*)d_in[7];
    const float* gamma = (const float*)d_in[8];
    const float* beta  = (const float*)d_in[9];
    float* outf = (float*)d_out;

    char* ws = (char*)d_ws;
    size_t off = 0;
    auto alloc = [&](size_t bytes) -> void* {
        void* p = ws + off;
        off += (bytes + 255) & ~size_t(255);
        return p;
    };
    unsigned* curb = (unsigned*)alloc((size_t)N_NODES * 64 * 4);
    unsigned* xlh  = (unsigned*)alloc((size_t)4 * N_NODES * 16 * 4);
    unsigned* xrh  = (unsigned*)alloc((size_t)4 * N_NODES * 16 * 4);
    unsigned* aggh = (unsigned*)alloc((size_t)4 * N_NODES * 16 * 4);
    ushort* Wt     = (ushort*)alloc((size_t)NLAYER * 2 * DIM * DIM * 2);
    // contiguous zero region: zbase (deg,cnt,bsum,bcarry) then esrc (incl. pads)
    size_t zoff0 = off;
    int* zbase     = (int*)alloc((size_t)(2 * N_NODES + 2 * 64) * 4);
    int* esrc      = (int*)alloc((size_t)EPAD * 4);
    size_t zbytes = (ws + off) - (char*)zbase;
    int* deg = zbase, *cnt = zbase + N_NODES;
    int* bsum = cnt + N_NODES, *bcarry = bsum + 64;
    int* rowptr    = (int*)alloc((size_t)(N_NODES + 1) * 4);
    int* blockhist = (int*)alloc((size_t)NSCAN * 256 * 4);
    int* bboff     = (int*)alloc((size_t)NSCAN * 256 * 4);
    int* order     = (int*)alloc((size_t)N_NODES * 4);
    float2* params = (float2*)alloc((size_t)NLAYER * 256 * sizeof(float2));
    (void)zoff0;

    const int* srcArr = ei;
    const int* dstArr = ei + N_EDGES;

    int n4 = (int)(zbytes / 16);
    zerofill<<<(n4 + 255) / 256, 256, 0, stream>>>((int4*)zbase, n4);
    fusedinit<<<15385, 256, 0, stream>>>(x, curb, Wl, Wr, Wt, dstArr, deg,
                                         att, bias, gamma, beta, params);
    scan1<<<NSCAN, 1024, 0, stream>>>(deg, rowptr, bsum, blockhist);
    midscan<<<1, 1024, 0, stream>>>(bsum, bcarry, blockhist, bboff);
    scan2<<<NSCAN, 1024, 0, stream>>>(rowptr, bcarry, deg, bboff, order);
    scatter_kernel<<<(N_EDGES + 255) / 256, 256, 0, stream>>>(srcArr, dstArr, rowptr, cnt, esrc);

    for (int l = 0; l < NLAYER; ++l) {
        gemm_mfma<<<dim3((N_NODES + 127) / 128, 2), 256, 0, stream>>>(
            (const ushort*)curb, Wt + (size_t)l * 2 * DIM * DIM,
            bl + (size_t)l * DIM, br + (size_t)l * DIM, xlh, xrh);
        agg_head<<<50000, 256, 0, stream>>>(
            xlh, xrh, esrc, rowptr, deg, order, params + (size_t)l * 256, aggh);
        ln_res<<<12500, 256, 0, stream>>>(
            aggh, params + (size_t)l * 256, curb, outf, l == NLAYER - 1 ? 1 : 0);
    }
}

// Round 10
// 348.391 us; speedup vs baseline: 1.2538x; 1.2538x over previous
//
#include <hip/hip_runtime.h>
#include <hip/hip_bf16.h>
#include <math.h>

#define N_NODES 50000
#define N_EDGES 640000
#define EPAD (N_EDGES + 4 * N_NODES)   // CSR padded to multiples of 4 per node
#define DIM 128
#define NLAYER 3
#define LN_EPS 1e-5f
#define LOG2E 1.44269504088896f
#define NSCAN 49   // ceil(50000/1024)

#if __has_builtin(__builtin_amdgcn_exp2f)
#define EXP2(x) __builtin_amdgcn_exp2f(x)
#else
#define EXP2(x) exp2f(x)
#endif

typedef __attribute__((ext_vector_type(8))) short bf16x8;
typedef __attribute__((ext_vector_type(4))) float f32x4;

__device__ inline ushort f2b(float f) {
    __hip_bfloat16 h = __float2bfloat16(f);
    return *reinterpret_cast<ushort*>(&h);
}
__device__ inline float bf_lo(unsigned u) { return __uint_as_float(u << 16); }
__device__ inline float bf_hi(unsigned u) { return __uint_as_float(u & 0xffff0000u); }
// leaky_relu(t) = 0.6t + 0.4|t|  (NEG_SLOPE=0.2)
__device__ inline float lr(float t) { return fmaf(0.4f, fabsf(t), 0.6f * t); }
__device__ inline unsigned pack2(float a, float b) {
    return (unsigned)f2b(a) | ((unsigned)f2b(b) << 16);
}
// packed word w of a node row holds channels (cw, cw+16); head = w>>4.
__device__ inline int cw_of(int w) { return (w & 15) + 32 * (w >> 4); }

// DPP-based add of cross-lane neighbor (VALU, no LDS pipe).
template<int CTRL>
__device__ inline float dppadd(float v) {
    int m = __builtin_amdgcn_update_dpp(0, __float_as_int(v), CTRL, 0xF, 0xF, true);
    return v + __int_as_float(m);
}
// sum over each 16-lane group
__device__ inline float reduce16(float v) {
    v = dppadd<0x124>(v);   // row_ror:4
    v = dppadd<0x128>(v);   // row_ror:8
    v = dppadd<0xB1>(v);    // quad_perm [1,0,3,2]
    v = dppadd<0x4E>(v);    // quad_perm [2,3,0,1]
    return v;
}

// ---------------- zero-fill (zbase + esrc pads, contiguous region) ----------------

__global__ __launch_bounds__(256) void zerofill(int4* __restrict__ p, int n4) {
    int i = blockIdx.x * 256 + threadIdx.x;
    if (i < n4) p[i] = make_int4(0, 0, 0, 0);
}

// ---------------- fused init: curb pack + Wt convert(k-perm) + deg hist + params ----

__global__ __launch_bounds__(256) void fusedinit(
    const float* __restrict__ x, unsigned* __restrict__ curb,
    const float* __restrict__ Wl, const float* __restrict__ Wr, ushort* __restrict__ Wt,
    const int* __restrict__ dst, int* __restrict__ deg,
    const float* __restrict__ att, const float* __restrict__ bias,
    const float* __restrict__ gamma, const float* __restrict__ beta,
    float2* __restrict__ params)
{
    int b = blockIdx.x, t = threadIdx.x;
    if (b < 12500) {
        int i = b * 256 + t;                 // i < N*64
        int node = i >> 6, w = i & 63;
        int c = cw_of(w);
        curb[i] = pack2(x[node * DIM + c], x[node * DIM + c + 16]);
    } else if (b < 12884) {
        int i = (b - 12500) * 256 + t;
        if (i < NLAYER * 2 * DIM * DIM) {
            int p = i & 127, n = (i >> 7) & 127, mat = (i >> 14) & 1, l = i >> 15;
            int c = cw_of(p >> 1) + (p & 1) * 16;
            const float* W = mat ? Wr : Wl;
            Wt[i] = f2b(W[l * DIM * DIM + c * DIM + n]);
        }
    } else if (b < 15384) {
        int e = (b - 12884) * 256 + t;       // e < 640000 exactly
        atomicAdd(&deg[dst[e]], 1);
    } else {
        int i = t;
        if (i < NLAYER * 64) {
            int l = i >> 6, w = i & 63;
            int c = cw_of(w);
            const float* A = att + l * DIM;
            const float* B = bias + l * DIM;
            const float* G = gamma + l * DIM;
            const float* E = beta + l * DIM;
            params[l * 256 + w]       = make_float2(A[c] * LOG2E, A[c + 16] * LOG2E);
            params[l * 256 + 64 + w]  = make_float2(B[c], B[c + 16]);
            params[l * 256 + 128 + w] = make_float2(G[c], G[c + 16]);
            params[l * 256 + 192 + w] = make_float2(E[c], E[c + 16]);
        }
    }
}

// ---------------- CSR build (padded to x4) + contention-free counting sort ----------

__global__ __launch_bounds__(1024) void scan1(const int* __restrict__ deg,
                                              int* __restrict__ rowptr,
                                              int* __restrict__ bsum,
                                              int* __restrict__ blockhist) {
    __shared__ int sd[1024];
    __shared__ int lh[256];
    int t = threadIdx.x;
    int idx = blockIdx.x * 1024 + t;
    if (t < 256) lh[t] = 0;
    __syncthreads();
    int v = (idx < N_NODES) ? deg[idx] : 0;
    if (idx < N_NODES) atomicAdd(&lh[v < 255 ? v : 255], 1);
    sd[t] = (v + 3) & ~3;                 // padded degree for CSR slots
    __syncthreads();
    for (int off = 1; off < 1024; off <<= 1) {
        int add = (t >= off) ? sd[t - off] : 0;
        __syncthreads();
        sd[t] += add;
        __syncthreads();
    }
    if (idx < N_NODES) rowptr[idx + 1] = sd[t];
    if (t == 1023) bsum[blockIdx.x] = sd[1023];
    if (t < 256) blockhist[blockIdx.x * 256 + t] = lh[t];
}

__global__ __launch_bounds__(1024) void midscan(const int* __restrict__ bsum,
                                                int* __restrict__ bcarry,
                                                const int* __restrict__ blockhist,
                                                int* __restrict__ bboff) {
    __shared__ int sh[256];
    int t = threadIdx.x;
    if (t < 256) {
        int tot = 0;
        for (int b = 0; b < NSCAN; ++b) tot += blockhist[b * 256 + t];
        sh[t] = tot;
    }
    __syncthreads();
    for (int off = 1; off < 256; off <<= 1) {
        int add = 0;
        if (t < 256 && t >= off) add = sh[t - off];
        __syncthreads();
        if (t < 256) sh[t] += add;
        __syncthreads();
    }
    if (t < 256) {
        int run = sh[255] - sh[t];          // heavy-first
        for (int b = 0; b < NSCAN; ++b) {
            bboff[b * 256 + t] = run;
            run += blockhist[b * 256 + t];
        }
    }
    if (t == 0) {
        int c = 0;
        for (int b = 0; b < NSCAN; ++b) { bcarry[b] = c; c += bsum[b]; }
    }
}

__global__ __launch_bounds__(1024) void scan2(int* __restrict__ rowptr,
                                              const int* __restrict__ bcarry,
                                              const int* __restrict__ deg,
                                              const int* __restrict__ bboff,
                                              int* __restrict__ order) {
    __shared__ int lh[256];
    int t = threadIdx.x;
    int idx = blockIdx.x * 1024 + t;
    if (t < 256) lh[t] = 0;
    __syncthreads();
    int carry = bcarry[blockIdx.x];
    if (idx == 0) rowptr[0] = 0;
    if (idx < N_NODES) {
        rowptr[idx + 1] += carry;
        int d = deg[idx];
        int bin = d < 255 ? d : 255;
        int rank = atomicAdd(&lh[bin], 1);
        order[bboff[blockIdx.x * 256 + bin] + rank] = idx;
    }
}

// esrc: BYTE offsets (src*64) into head slices; pads stay 0 (masked later).
// Also fills slotinfo[slot] = (node, e0, deg) so agg setup is ONE s_load.
__global__ void scatter_kernel(const int* __restrict__ src, const int* __restrict__ dst,
                               const int* __restrict__ rowptr, int* __restrict__ cnt,
                               int* __restrict__ esrc,
                               const int* __restrict__ order, const int* __restrict__ deg,
                               int4* __restrict__ slotinfo) {
    int e = blockIdx.x * blockDim.x + threadIdx.x;
    if (e < N_EDGES) {
        int d = dst[e];
        int pos = rowptr[d] + atomicAdd(&cnt[d], 1);
        esrc[pos] = src[e] << 6;
    }
    if (e < N_NODES) {
        int nd = order[e];
        slotinfo[e] = make_int4(nd, rowptr[nd], deg[nd], 0);
    }
}

// ---------------- MFMA GEMM: head-major packed output [4][N][16] ----------------

__global__ __launch_bounds__(256) void gemm_mfma(
    const ushort* __restrict__ A,      // [N][128] bf16, k-permuted packed order
    const ushort* __restrict__ Wt_l,   // [2][128n][128kperm] bf16
    const float* __restrict__ bl, const float* __restrict__ br,
    unsigned* __restrict__ xlh, unsigned* __restrict__ xrh)
{
    int mat = blockIdx.y;
    int rowbase = blockIdx.x * 128;
    int wid = threadIdx.x >> 6;
    int lane = threadIdx.x & 63;
    int wr = wid >> 1, wc = wid & 1;
    int m0 = rowbase + wr * 64, n0 = wc * 64;

    const ushort* W = Wt_l + mat * DIM * DIM;
    const float* bias = mat ? br : bl;
    unsigned* out = mat ? xrh : xlh;

    int fr = lane & 15;
    int kg = lane >> 4;

    bf16x8 af[4][4], bfr[4][4];
    #pragma unroll
    for (int mf = 0; mf < 4; ++mf) {
        int row = m0 + mf * 16 + fr;
        if (row > N_NODES - 1) row = N_NODES - 1;
        const ushort* p = A + (size_t)row * DIM + kg * 8;
        #pragma unroll
        for (int kf = 0; kf < 4; ++kf)
            af[mf][kf] = *reinterpret_cast<const bf16x8*>(p + kf * 32);
    }
    #pragma unroll
    for (int nf = 0; nf < 4; ++nf) {
        const ushort* p = W + (size_t)(n0 + nf * 16 + fr) * DIM + kg * 8;
        #pragma unroll
        for (int kf = 0; kf < 4; ++kf)
            bfr[nf][kf] = *reinterpret_cast<const bf16x8*>(p + kf * 32);
    }

    f32x4 acc[4][4];
    #pragma unroll
    for (int mf = 0; mf < 4; ++mf)
        #pragma unroll
        for (int nf = 0; nf < 4; ++nf)
            acc[mf][nf] = (f32x4){0.f, 0.f, 0.f, 0.f};

    #pragma unroll
    for (int kf = 0; kf < 4; ++kf)
        #pragma unroll
        for (int mf = 0; mf < 4; ++mf)
            #pragma unroll
            for (int nf = 0; nf < 4; ++nf)
                acc[mf][nf] = __builtin_amdgcn_mfma_f32_16x16x32_bf16(
                    af[mf][kf], bfr[nf][kf], acc[mf][nf], 0, 0, 0);

    int col = lane & 15;
    int r4 = lane >> 4;
    float bb[4];
    #pragma unroll
    for (int nf = 0; nf < 4; ++nf) bb[nf] = bias[n0 + nf * 16 + col];

    #pragma unroll
    for (int mf = 0; mf < 4; ++mf) {
        #pragma unroll
        for (int pj = 0; pj < 2; ++pj) {
            // channels c=64wc+32pj+col, c+16 -> head h=2wc+pj, word col
            int h = 2 * wc + pj;
            #pragma unroll
            for (int r = 0; r < 4; ++r) {
                int row = m0 + mf * 16 + r4 * 4 + r;
                if (row < N_NODES)
                    out[((size_t)(h * N_NODES + row) << 4) + col] =
                        pack2(acc[mf][2 * pj][r] + bb[2 * pj],
                              acc[mf][2 * pj + 1][r] + bb[2 * pj + 1]);
            }
        }
    }
}

// ---------------- fused aggregation: wave=node, 4 sequential head sub-loops ------
// lanes = 16 words x 4 edge-slots; per-head working set 3.2MB -> L2-resident.

__global__ __launch_bounds__(256) void agg_kernel(
    const unsigned* __restrict__ xlh, const unsigned* __restrict__ xrh,
    const int* __restrict__ esrc, const int4* __restrict__ slotinfo,
    const float2* __restrict__ P4,
    unsigned* __restrict__ curb, float* __restrict__ outf, int last)
{
    int slot = blockIdx.x * 4 + (threadIdx.x >> 6);
    int lane = threadIdx.x & 63;
    int ww = lane & 15, q = lane >> 4;
    int4 si = slotinfo[slot];                       // wave-uniform -> scalar load
    int node = __builtin_amdgcn_readfirstlane(si.x);
    int e0   = __builtin_amdgcn_readfirstlane(si.y);
    int dt   = __builtin_amdgcn_readfirstlane(si.z);
    int nit  = (dt + 3) >> 2;
    int laneoff = ww << 2;

    float oxF = 0.f, oyF = 0.f;
    #pragma unroll
    for (int h = 0; h < 4; ++h) {
        const char* xb = (const char*)xlh + (size_t)h * (N_NODES * 64);
        float2 att2 = P4[(h << 4) | ww];
        unsigned xru = xrh[((size_t)(h * N_NODES + node) << 4) + ww];
        float xrx = bf_lo(xru), xry = bf_hi(xru);

        float s = 0.f, ox = 0.f, oy = 0.f;
        if (nit > 0) {
            int4 jj = *reinterpret_cast<const int4*>(esrc + e0);
            int j = q == 0 ? jj.x : q == 1 ? jj.y : q == 2 ? jj.z : jj.w;
            unsigned u = *(const unsigned*)(xb + j + laneoff);
            for (int it = 0; it < nit; ++it) {
                unsigned un = 0;
                if (it + 1 < nit) {
                    int4 jn = *reinterpret_cast<const int4*>(esrc + e0 + (it + 1) * 4);
                    int j2 = q == 0 ? jn.x : q == 1 ? jn.y : q == 2 ? jn.z : jn.w;
                    un = *(const unsigned*)(xb + j2 + laneoff);   // next batch in flight
                }
                float vx = bf_lo(u), vy = bf_hi(u);
                float p = fmaf(lr(vy + xry), att2.y, lr(vx + xrx) * att2.x);
                p = reduce16(p);
                float w = (q < dt - it * 4) ? EXP2(p) : 0.f;      // mask pad slots
                s += w; ox = fmaf(w, vx, ox); oy = fmaf(w, vy, oy);
                u = un;
            }
        }
        // fold the 4 edge-slot groups
        s  += __shfl_xor(s, 16);  s  += __shfl_xor(s, 32);
        ox += __shfl_xor(ox, 16); ox += __shfl_xor(ox, 32);
        oy += __shfl_xor(oy, 16); oy += __shfl_xor(oy, 32);
        float inv = 1.f / (s + 1e-16f);
        if (q == h) { oxF = ox * inv; oyF = oy * inv; }
    }

    // bias + relu + LayerNorm + residual
    float2 b2 = P4[64 + lane];
    float gx = fmaxf(oxF + b2.x, 0.f);
    float gy = fmaxf(oyF + b2.y, 0.f);

    float sum = gx + gy;
    sum = reduce16(sum);
    sum += __shfl_xor(sum, 16);
    sum += __shfl_xor(sum, 32);
    float mu = sum * (1.f / 128.f);
    float dx = gx - mu, dy = gy - mu;
    float ss = dx * dx + dy * dy;
    ss = reduce16(ss);
    ss += __shfl_xor(ss, 16);
    ss += __shfl_xor(ss, 32);
    float rstd = rsqrtf(ss * (1.f / 128.f) + LN_EPS);

    float2 g2  = P4[128 + lane];
    float2 be2 = P4[192 + lane];
    unsigned old = curb[node * 64 + lane];
    float yx = fmaf(dx * rstd, g2.x, be2.x) + bf_lo(old);
    float yy = fmaf(dy * rstd, g2.y, be2.y) + bf_hi(old);

    if (last) {
        int c = cw_of(lane);
        outf[node * DIM + c] = yx;
        outf[node * DIM + c + 16] = yy;
    } else {
        curb[node * 64 + lane] = pack2(yx, yy);
    }
}

// ---------------- launch ----------------

extern "C" void kernel_launch(void* const* d_in, const int* in_sizes, int n_in,
                              void* d_out, int out_size, void* d_ws, size_t ws_size,
                              hipStream_t stream) {
    const float* x     = (const float*)d_in[0];
    const int*   ei    = (const int*)d_in[1];
    const float* Wl    = (const float*)d_in[2];
    const float* bl    = (const float*)d_in[3];
    const float* Wr    = (const float*)d_in[4];
    const float* br    = (const float*)d_in[5];
    const float* att   = (const float*)d_in[6];
    const float* bias  = (const float*)d_in[7];
    const float* gamma = (const float*)d_in[8];
    const float* beta  = (const float*)d_in[9];
    float* outf = (float*)d_out;

    char* ws = (char*)d_ws;
    size_t off = 0;
    auto alloc = [&](size_t bytes) -> void* {
        void* p = ws + off;
        off += (bytes + 255) & ~size_t(255);
        return p;
    };
    unsigned* curb = (unsigned*)alloc((size_t)N_NODES * 64 * 4);
    unsigned* xlh  = (unsigned*)alloc((size_t)4 * N_NODES * 16 * 4);
    unsigned* xrh  = (unsigned*)alloc((size_t)4 * N_NODES * 16 * 4);
    ushort* Wt     = (ushort*)alloc((size_t)NLAYER * 2 * DIM * DIM * 2);
    // contiguous zero region: zbase (deg,cnt,bsum,bcarry) then esrc (incl. pads)
    int* zbase     = (int*)alloc((size_t)(2 * N_NODES + 2 * 64) * 4);
    int* esrc      = (int*)alloc((size_t)EPAD * 4);
    size_t zbytes = (ws + off) - (char*)zbase;
    int* deg = zbase, *cnt = zbase + N_NODES;
    int* bsum = cnt + N_NODES, *bcarry = bsum + 64;
    int* rowptr    = (int*)alloc((size_t)(N_NODES + 1) * 4);
    int* blockhist = (int*)alloc((size_t)NSCAN * 256 * 4);
    int* bboff     = (int*)alloc((size_t)NSCAN * 256 * 4);
    int* order     = (int*)alloc((size_t)N_NODES * 4);
    int4* slotinfo = (int4*)alloc((size_t)N_NODES * 16);
    float2* params = (float2*)alloc((size_t)NLAYER * 256 * sizeof(float2));

    const int* srcArr = ei;
    const int* dstArr = ei + N_EDGES;

    int n4 = (int)(zbytes / 16);
    zerofill<<<(n4 + 255) / 256, 256, 0, stream>>>((int4*)zbase, n4);
    fusedinit<<<15385, 256, 0, stream>>>(x, curb, Wl, Wr, Wt, dstArr, deg,
                                         att, bias, gamma, beta, params);
    scan1<<<NSCAN, 1024, 0, stream>>>(deg, rowptr, bsum, blockhist);
    midscan<<<1, 1024, 0, stream>>>(bsum, bcarry, blockhist, bboff);
    scan2<<<NSCAN, 1024, 0, stream>>>(rowptr, bcarry, deg, bboff, order);
    scatter_kernel<<<(N_EDGES + 255) / 256, 256, 0, stream>>>(
        srcArr, dstArr, rowptr, cnt, esrc, order, deg, slotinfo);

    for (int l = 0; l < NLAYER; ++l) {
        gemm_mfma<<<dim3((N_NODES + 127) / 128, 2), 256, 0, stream>>>(
            (const ushort*)curb, Wt + (size_t)l * 2 * DIM * DIM,
            bl + (size_t)l * DIM, br + (size_t)l * DIM, xlh, xrh);
        agg_kernel<<<12500, 256, 0, stream>>>(
            xlh, xrh, esrc, slotinfo, params + (size_t)l * 256,
            curb, outf, l == NLAYER - 1 ? 1 : 0);
    }
}

// Round 11
// 270.049 us; speedup vs baseline: 1.6175x; 1.2901x over previous
//
#include <hip/hip_runtime.h>
#include <hip/hip_bf16.h>
#include <math.h>

#define N_NODES 50000
#define N_EDGES 640000
#define DIM 128
#define NLAYER 3
#define LN_EPS 1e-5f
#define LOG2E 1.44269504088896f
#define NSCAN 49   // ceil(50000/1024)

#if __has_builtin(__builtin_amdgcn_exp2f)
#define EXP2(x) __builtin_amdgcn_exp2f(x)
#else
#define EXP2(x) exp2f(x)
#endif

typedef __attribute__((ext_vector_type(8))) short bf16x8;
typedef __attribute__((ext_vector_type(4))) float f32x4;

__device__ inline ushort f2b(float f) {
    __hip_bfloat16 h = __float2bfloat16(f);
    return *reinterpret_cast<ushort*>(&h);
}
__device__ inline float bf_lo(unsigned u) { return __uint_as_float(u << 16); }
__device__ inline float bf_hi(unsigned u) { return __uint_as_float(u & 0xffff0000u); }
// leaky_relu(t) = 0.6t + 0.4|t|  (NEG_SLOPE=0.2)
__device__ inline float lr(float t) { return fmaf(0.4f, fabsf(t), 0.6f * t); }
__device__ inline unsigned pack2(float a, float b) {
    return (unsigned)f2b(a) | ((unsigned)f2b(b) << 16);
}
// packed word w of a node row holds channels (cw, cw+16); both in same head.
__device__ inline int cw_of(int w) { return (w & 15) + 32 * (w >> 4); }

// DPP-based add of cross-lane neighbor (VALU, no LDS pipe).
template<int CTRL>
__device__ inline float dppadd(float v) {
    int m = __builtin_amdgcn_update_dpp(0, __float_as_int(v), CTRL, 0xF, 0xF, true);
    return v + __int_as_float(m);
}
// sum over each 16-lane group
__device__ inline float reduce16(float v) {
    v = dppadd<0x124>(v);   // row_ror:4
    v = dppadd<0x128>(v);   // row_ror:8
    v = dppadd<0xB1>(v);    // quad_perm [1,0,3,2]
    v = dppadd<0x4E>(v);    // quad_perm [2,3,0,1]
    return v;
}

// ---------------- zero-fill ----------------

__global__ __launch_bounds__(256) void zerofill(int4* __restrict__ p, int n4) {
    int i = blockIdx.x * 256 + threadIdx.x;
    if (i < n4) p[i] = make_int4(0, 0, 0, 0);
}

// ---------------- fused init: curb pack + Wt convert(k-perm) + deg hist + params ----

__global__ __launch_bounds__(256) void fusedinit(
    const float* __restrict__ x, unsigned* __restrict__ curb,
    const float* __restrict__ Wl, const float* __restrict__ Wr, ushort* __restrict__ Wt,
    const int* __restrict__ dst, int* __restrict__ deg,
    const float* __restrict__ att, const float* __restrict__ bias,
    const float* __restrict__ gamma, const float* __restrict__ beta,
    float2* __restrict__ params)
{
    int b = blockIdx.x, t = threadIdx.x;
    if (b < 12500) {
        int i = b * 256 + t;                 // i < N*64
        int node = i >> 6, w = i & 63;
        int c = cw_of(w);
        curb[i] = pack2(x[node * DIM + c], x[node * DIM + c + 16]);
    } else if (b < 12884) {
        int i = (b - 12500) * 256 + t;
        if (i < NLAYER * 2 * DIM * DIM) {
            int p = i & 127, n = (i >> 7) & 127, mat = (i >> 14) & 1, l = i >> 15;
            int c = cw_of(p >> 1) + (p & 1) * 16;
            const float* W = mat ? Wr : Wl;
            Wt[i] = f2b(W[l * DIM * DIM + c * DIM + n]);
        }
    } else if (b < 15384) {
        int e = (b - 12884) * 256 + t;       // e < 640000 exactly
        atomicAdd(&deg[dst[e]], 1);
    } else {
        int i = t;
        if (i < NLAYER * 64) {
            int l = i >> 6, w = i & 63;
            int c = cw_of(w);
            const float* A = att + l * DIM;
            const float* B = bias + l * DIM;
            const float* G = gamma + l * DIM;
            const float* E = beta + l * DIM;
            params[l * 256 + w]       = make_float2(A[c] * LOG2E, A[c + 16] * LOG2E);
            params[l * 256 + 64 + w]  = make_float2(B[c], B[c + 16]);
            params[l * 256 + 128 + w] = make_float2(G[c], G[c + 16]);
            params[l * 256 + 192 + w] = make_float2(E[c], E[c + 16]);
        }
    }
}

// ---------------- CSR build + contention-free counting sort ----------------

__global__ __launch_bounds__(1024) void scan1(const int* __restrict__ deg,
                                              int* __restrict__ rowptr,
                                              int* __restrict__ bsum,
                                              int* __restrict__ blockhist) {
    __shared__ int sd[1024];
    __shared__ int lh[256];
    int t = threadIdx.x;
    int idx = blockIdx.x * 1024 + t;
    if (t < 256) lh[t] = 0;
    __syncthreads();
    int v = (idx < N_NODES) ? deg[idx] : 0;
    if (idx < N_NODES) atomicAdd(&lh[v < 255 ? v : 255], 1);
    sd[t] = v;
    __syncthreads();
    for (int off = 1; off < 1024; off <<= 1) {
        int add = (t >= off) ? sd[t - off] : 0;
        __syncthreads();
        sd[t] += add;
        __syncthreads();
    }
    if (idx < N_NODES) rowptr[idx + 1] = sd[t];
    if (t == 1023) bsum[blockIdx.x] = sd[1023];
    if (t < 256) blockhist[blockIdx.x * 256 + t] = lh[t];
}

__global__ __launch_bounds__(1024) void midscan(const int* __restrict__ bsum,
                                                int* __restrict__ bcarry,
                                                const int* __restrict__ blockhist,
                                                int* __restrict__ bboff) {
    __shared__ int sh[256];
    int t = threadIdx.x;
    if (t < 256) {
        int tot = 0;
        for (int b = 0; b < NSCAN; ++b) tot += blockhist[b * 256 + t];
        sh[t] = tot;
    }
    __syncthreads();
    for (int off = 1; off < 256; off <<= 1) {
        int add = 0;
        if (t < 256 && t >= off) add = sh[t - off];
        __syncthreads();
        if (t < 256) sh[t] += add;
        __syncthreads();
    }
    if (t < 256) {
        int run = sh[255] - sh[t];          // heavy-first
        for (int b = 0; b < NSCAN; ++b) {
            bboff[b * 256 + t] = run;
            run += blockhist[b * 256 + t];
        }
    }
    if (t == 0) {
        int c = 0;
        for (int b = 0; b < NSCAN; ++b) { bcarry[b] = c; c += bsum[b]; }
    }
}

__global__ __launch_bounds__(1024) void scan2(int* __restrict__ rowptr,
                                              const int* __restrict__ bcarry,
                                              const int* __restrict__ deg,
                                              const int* __restrict__ bboff,
                                              int* __restrict__ order) {
    __shared__ int lh[256];
    int t = threadIdx.x;
    int idx = blockIdx.x * 1024 + t;
    if (t < 256) lh[t] = 0;
    __syncthreads();
    int carry = bcarry[blockIdx.x];
    if (idx == 0) rowptr[0] = 0;
    if (idx < N_NODES) {
        rowptr[idx + 1] += carry;
        int d = deg[idx];
        int bin = d < 255 ? d : 255;
        int rank = atomicAdd(&lh[bin], 1);
        order[bboff[blockIdx.x * 256 + bin] + rank] = idx;
    }
}

// esrc: BYTE offsets (src*256) into packed [N][64] rows.
// Also fills slotinfo[slot] = (node, e0, e1) so agg setup is ONE scalar load.
__global__ void scatter_kernel(const int* __restrict__ src, const int* __restrict__ dst,
                               const int* __restrict__ rowptr, int* __restrict__ cnt,
                               int* __restrict__ esrc,
                               const int* __restrict__ order, const int* __restrict__ deg,
                               int4* __restrict__ slotinfo) {
    int e = blockIdx.x * blockDim.x + threadIdx.x;
    if (e < N_EDGES) {
        int d = dst[e];
        int pos = rowptr[d] + atomicAdd(&cnt[d], 1);
        esrc[pos] = src[e] << 8;
    }
    if (e < N_NODES) {
        int nd = order[e];
        int r0 = rowptr[nd];
        slotinfo[e] = make_int4(nd, r0, r0 + deg[nd], 0);
    }
}

// ---------------- MFMA GEMM: {xlb,xrb} = bf16(curb @ W + b), packed-pair output ----

__global__ __launch_bounds__(256) void gemm_mfma(
    const ushort* __restrict__ A,      // [N][128] bf16, k-permuted packed order
    const ushort* __restrict__ Wt_l,   // [2][128n][128kperm] bf16
    const float* __restrict__ bl, const float* __restrict__ br,
    unsigned* __restrict__ xlb, unsigned* __restrict__ xrb)
{
    int mat = blockIdx.y;
    int rowbase = blockIdx.x * 128;
    int wid = threadIdx.x >> 6;
    int lane = threadIdx.x & 63;
    int wr = wid >> 1, wc = wid & 1;
    int m0 = rowbase + wr * 64, n0 = wc * 64;

    const ushort* W = Wt_l + mat * DIM * DIM;
    const float* bias = mat ? br : bl;
    unsigned* out = mat ? xrb : xlb;

    int fr = lane & 15;
    int kg = lane >> 4;

    bf16x8 af[4][4], bfr[4][4];
    #pragma unroll
    for (int mf = 0; mf < 4; ++mf) {
        int row = m0 + mf * 16 + fr;
        if (row > N_NODES - 1) row = N_NODES - 1;
        const ushort* p = A + (size_t)row * DIM + kg * 8;
        #pragma unroll
        for (int kf = 0; kf < 4; ++kf)
            af[mf][kf] = *reinterpret_cast<const bf16x8*>(p + kf * 32);
    }
    #pragma unroll
    for (int nf = 0; nf < 4; ++nf) {
        const ushort* p = W + (size_t)(n0 + nf * 16 + fr) * DIM + kg * 8;
        #pragma unroll
        for (int kf = 0; kf < 4; ++kf)
            bfr[nf][kf] = *reinterpret_cast<const bf16x8*>(p + kf * 32);
    }

    f32x4 acc[4][4];
    #pragma unroll
    for (int mf = 0; mf < 4; ++mf)
        #pragma unroll
        for (int nf = 0; nf < 4; ++nf)
            acc[mf][nf] = (f32x4){0.f, 0.f, 0.f, 0.f};

    #pragma unroll
    for (int kf = 0; kf < 4; ++kf)
        #pragma unroll
        for (int mf = 0; mf < 4; ++mf)
            #pragma unroll
            for (int nf = 0; nf < 4; ++nf)
                acc[mf][nf] = __builtin_amdgcn_mfma_f32_16x16x32_bf16(
                    af[mf][kf], bfr[nf][kf], acc[mf][nf], 0, 0, 0);

    int col = lane & 15;
    int r4 = lane >> 4;
    float bb[4];
    #pragma unroll
    for (int nf = 0; nf < 4; ++nf) bb[nf] = bias[n0 + nf * 16 + col];

    #pragma unroll
    for (int mf = 0; mf < 4; ++mf) {
        #pragma unroll
        for (int pj = 0; pj < 2; ++pj) {
            // channels c = 64*wc + 32*pj + col, c+16 -> word w = col + 32*wc + 16*pj
            int w = col + 32 * wc + 16 * pj;
            #pragma unroll
            for (int r = 0; r < 4; ++r) {
                int row = m0 + mf * 16 + r4 * 4 + r;
                if (row < N_NODES)
                    out[(size_t)row * 64 + w] =
                        pack2(acc[mf][2 * pj][r] + bb[2 * pj],
                              acc[mf][2 * pj + 1][r] + bb[2 * pj + 1]);
            }
        }
    }
}

// ---------------- fused aggregation: r8 structure + slotinfo + hoisted epilogue ----

__device__ inline void gather8(const char* __restrict__ xb, int laneoff,
                               const int j[8], unsigned u[8]) {
    #pragma unroll
    for (int i = 0; i < 8; ++i)
        u[i] = *(const unsigned*)(xb + j[i] + laneoff);
}

__device__ inline void compute8(const unsigned u[8], float ax, float ay,
                                float xrx, float xry,
                                float& s, float& ox, float& oy) {
    #pragma unroll
    for (int i = 0; i < 8; ++i) {
        float vx = bf_lo(u[i]), vy = bf_hi(u[i]);
        float p = lr(vx + xrx) * ax + lr(vy + xry) * ay;
        p = reduce16(p);
        float w = EXP2(p);
        s += w; ox = fmaf(w, vx, ox); oy = fmaf(w, vy, oy);
    }
}

__device__ inline void computeT(const unsigned u[8], float ax, float ay,
                                float xrx, float xry,
                                float& s, float& ox, float& oy, int rem) {
    #pragma unroll
    for (int i = 0; i < 8; ++i) {
        if (i < rem) {     // wave-uniform predicate
            float vx = bf_lo(u[i]), vy = bf_hi(u[i]);
            float p = lr(vx + xrx) * ax + lr(vy + xry) * ay;
            p = reduce16(p);
            float w = EXP2(p);
            s += w; ox = fmaf(w, vx, ox); oy = fmaf(w, vy, oy);
        }
    }
}

__global__ __launch_bounds__(256) void agg_kernel(
    const unsigned* __restrict__ xlb2, const unsigned* __restrict__ xrb2,
    const int* __restrict__ esrc, const int4* __restrict__ slotinfo,
    const float2* __restrict__ P4,
    unsigned* __restrict__ curb, float* __restrict__ outf, int last)
{
    int slot = blockIdx.x * 4 + (threadIdx.x >> 6);
    int lane = threadIdx.x & 63;
    int4 si = slotinfo[slot];
    int node = __builtin_amdgcn_readfirstlane(si.x);
    int e0   = __builtin_amdgcn_readfirstlane(si.y);
    int e1   = __builtin_amdgcn_readfirstlane(si.z);

    // hoisted loads: hide their latency under the edge loop
    unsigned xru = xrb2[node * 64 + lane];
    float2 att2 = P4[lane];
    float2 b2   = P4[64 + lane];
    float2 g2   = P4[128 + lane];
    float2 be2  = P4[192 + lane];
    unsigned old = curb[node * 64 + lane];
    float xrx = bf_lo(xru), xry = bf_hi(xru);

    const char* xb = (const char*)xlb2;
    int laneoff = lane << 2;

    float s = 0.f, ox = 0.f, oy = 0.f;
    int nb = (e1 - e0) >> 3;
    int rem = (e1 - e0) & 7;

    int jc[8], jn[8];
    unsigned uc[8], un[8];

    if (nb > 0) {
        #pragma unroll
        for (int i = 0; i < 8; ++i) jc[i] = esrc[e0 + i];   // uniform -> s_load
        gather8(xb, laneoff, jc, uc);
    }
    int ec = e0;
    for (int b = 1; b < nb; ++b) {
        int en = ec + 8;
        #pragma unroll
        for (int i = 0; i < 8; ++i) jn[i] = esrc[en + i];
        gather8(xb, laneoff, jn, un);          // next batch in flight
        compute8(uc, att2.x, att2.y, xrx, xry, s, ox, oy);
        #pragma unroll
        for (int i = 0; i < 8; ++i) uc[i] = un[i];
        ec = en;
    }
    if (nb > 0) {
        if (rem) {
            int et = ec + 8;
            #pragma unroll
            for (int i = 0; i < 8; ++i)
                jn[i] = esrc[et + (i < rem ? i : rem - 1)];
            gather8(xb, laneoff, jn, un);      // tail in flight
            compute8(uc, att2.x, att2.y, xrx, xry, s, ox, oy);
            computeT(un, att2.x, att2.y, xrx, xry, s, ox, oy, rem);
        } else {
            compute8(uc, att2.x, att2.y, xrx, xry, s, ox, oy);
        }
    } else if (rem) {
        #pragma unroll
        for (int i = 0; i < 8; ++i)
            jc[i] = esrc[e0 + (i < rem ? i : rem - 1)];
        gather8(xb, laneoff, jc, uc);
        computeT(uc, att2.x, att2.y, xrx, xry, s, ox, oy, rem);
    }

    float inv = 1.f / (s + 1e-16f);
    float gx = fmaxf(fmaf(ox, inv, b2.x), 0.f);
    float gy = fmaxf(fmaf(oy, inv, b2.y), 0.f);

    // LayerNorm over 128 channels
    float sum = gx + gy;
    sum = reduce16(sum);
    sum += __shfl_xor(sum, 16);
    sum += __shfl_xor(sum, 32);
    float mu = sum * (1.f / 128.f);
    float dx = gx - mu, dy = gy - mu;
    float ss = dx * dx + dy * dy;
    ss = reduce16(ss);
    ss += __shfl_xor(ss, 16);
    ss += __shfl_xor(ss, 32);
    float rstd = rsqrtf(ss * (1.f / 128.f) + LN_EPS);

    float yx = fmaf(dx * rstd, g2.x, be2.x) + bf_lo(old);
    float yy = fmaf(dy * rstd, g2.y, be2.y) + bf_hi(old);

    if (last) {
        int c = cw_of(lane);
        outf[node * DIM + c] = yx;
        outf[node * DIM + c + 16] = yy;
    } else {
        curb[node * 64 + lane] = pack2(yx, yy);
    }
}

// ---------------- launch ----------------

extern "C" void kernel_launch(void* const* d_in, const int* in_sizes, int n_in,
                              void* d_out, int out_size, void* d_ws, size_t ws_size,
                              hipStream_t stream) {
    const float* x     = (const float*)d_in[0];
    const int*   ei    = (const int*)d_in[1];
    const float* Wl    = (const float*)d_in[2];
    const float* bl    = (const float*)d_in[3];
    const float* Wr    = (const float*)d_in[4];
    const float* br    = (const float*)d_in[5];
    const float* att   = (const float*)d_in[6];
    const float* bias  = (const float*)d_in[7];
    const float* gamma = (const float*)d_in[8];
    const float* beta  = (const float*)d_in[9];
    float* outf = (float*)d_out;

    char* ws = (char*)d_ws;
    size_t off = 0;
    auto alloc = [&](size_t bytes) -> void* {
        void* p = ws + off;
        off += (bytes + 255) & ~size_t(255);
        return p;
    };
    unsigned* curb = (unsigned*)alloc((size_t)N_NODES * 64 * 4);
    unsigned* xlb  = (unsigned*)alloc((size_t)N_NODES * 64 * 4);
    unsigned* xrb  = (unsigned*)alloc((size_t)N_NODES * 64 * 4);
    ushort* Wt     = (ushort*)alloc((size_t)NLAYER * 2 * DIM * DIM * 2);
    int* esrc      = (int*)alloc((size_t)N_EDGES * 4);
    int* rowptr    = (int*)alloc((size_t)(N_NODES + 1) * 4);
    // contiguous zero region: deg, cnt, bsum, bcarry
    int* zbase     = (int*)alloc((size_t)(2 * N_NODES + 2 * 64) * 4);
    int* deg = zbase, *cnt = zbase + N_NODES;
    int* bsum = cnt + N_NODES, *bcarry = bsum + 64;
    int* blockhist = (int*)alloc((size_t)NSCAN * 256 * 4);
    int* bboff     = (int*)alloc((size_t)NSCAN * 256 * 4);
    int* order     = (int*)alloc((size_t)N_NODES * 4);
    int4* slotinfo = (int4*)alloc((size_t)N_NODES * 16);
    float2* params = (float2*)alloc((size_t)NLAYER * 256 * sizeof(float2));

    const int* srcArr = ei;
    const int* dstArr = ei + N_EDGES;

    int n4 = (2 * N_NODES + 2 * 64) / 4;
    zerofill<<<(n4 + 255) / 256, 256, 0, stream>>>((int4*)zbase, n4);
    fusedinit<<<15385, 256, 0, stream>>>(x, curb, Wl, Wr, Wt, dstArr, deg,
                                         att, bias, gamma, beta, params);
    scan1<<<NSCAN, 1024, 0, stream>>>(deg, rowptr, bsum, blockhist);
    midscan<<<1, 1024, 0, stream>>>(bsum, bcarry, blockhist, bboff);
    scan2<<<NSCAN, 1024, 0, stream>>>(rowptr, bcarry, deg, bboff, order);
    scatter_kernel<<<(N_EDGES + 255) / 256, 256, 0, stream>>>(
        srcArr, dstArr, rowptr, cnt, esrc, order, deg, slotinfo);

    for (int l = 0; l < NLAYER; ++l) {
        gemm_mfma<<<dim3((N_NODES + 127) / 128, 2), 256, 0, stream>>>(
            (const ushort*)curb, Wt + (size_t)l * 2 * DIM * DIM,
            bl + (size_t)l * DIM, br + (size_t)l * DIM, xlb, xrb);
        agg_kernel<<<12500, 256, 0, stream>>>(
            xlb, xrb, esrc, slotinfo, params + (size_t)l * 256,
            curb, outf, l == NLAYER - 1 ? 1 : 0);
    }
}

// Round 12
// 264.439 us; speedup vs baseline: 1.6518x; 1.0212x over previous
//
#include <hip/hip_runtime.h>
#include <hip/hip_bf16.h>
#include <math.h>

#define N_NODES 50000
#define N_EDGES 640000
#define DIM 128
#define NLAYER 3
#define LN_EPS 1e-5f
#define LOG2E 1.44269504088896f
#define NSCAN 49    // ceil(50000/1024)
#define NG 391      // ceil(50000/128) row-blocks per matrix
#define SCATB 2500  // scatter blocks (640000/256)

#if __has_builtin(__builtin_amdgcn_exp2f)
#define EXP2(x) __builtin_amdgcn_exp2f(x)
#else
#define EXP2(x) exp2f(x)
#endif

typedef __attribute__((ext_vector_type(8))) short bf16x8;
typedef __attribute__((ext_vector_type(4))) float f32x4;

__device__ inline ushort f2b(float f) {
    __hip_bfloat16 h = __float2bfloat16(f);
    return *reinterpret_cast<ushort*>(&h);
}
__device__ inline float bf_lo(unsigned u) { return __uint_as_float(u << 16); }
__device__ inline float bf_hi(unsigned u) { return __uint_as_float(u & 0xffff0000u); }
// leaky_relu(t) = 0.6t + 0.4|t|  (NEG_SLOPE=0.2)
__device__ inline float lr(float t) { return fmaf(0.4f, fabsf(t), 0.6f * t); }
__device__ inline unsigned pack2(float a, float b) {
    return (unsigned)f2b(a) | ((unsigned)f2b(b) << 16);
}
// packed word w of a node row holds channels (cw, cw+16); both in same head.
__device__ inline int cw_of(int w) { return (w & 15) + 32 * (w >> 4); }

// DPP-based add of cross-lane neighbor (VALU, no LDS pipe).
template<int CTRL>
__device__ inline float dppadd(float v) {
    int m = __builtin_amdgcn_update_dpp(0, __float_as_int(v), CTRL, 0xF, 0xF, true);
    return v + __int_as_float(m);
}
// sum over each 16-lane group
__device__ inline float reduce16(float v) {
    v = dppadd<0x124>(v);   // row_ror:4
    v = dppadd<0x128>(v);   // row_ror:8
    v = dppadd<0xB1>(v);    // quad_perm [1,0,3,2]
    v = dppadd<0x4E>(v);    // quad_perm [2,3,0,1]
    return v;
}

// ---------------- zero-fill ----------------

__global__ __launch_bounds__(256) void zerofill(int4* __restrict__ p, int n4) {
    int i = blockIdx.x * 256 + threadIdx.x;
    if (i < n4) p[i] = make_int4(0, 0, 0, 0);
}

// ---------------- fused init: curb pack + Wt convert(k-perm) + deg hist + params ----

__global__ __launch_bounds__(256) void fusedinit(
    const float* __restrict__ x, unsigned* __restrict__ curb,
    const float* __restrict__ Wl, const float* __restrict__ Wr, ushort* __restrict__ Wt,
    const int* __restrict__ dst, int* __restrict__ deg,
    const float* __restrict__ att, const float* __restrict__ bias,
    const float* __restrict__ gamma, const float* __restrict__ beta,
    float2* __restrict__ params)
{
    int b = blockIdx.x, t = threadIdx.x;
    if (b < 12500) {
        int i = b * 256 + t;                 // i < N*64
        int node = i >> 6, w = i & 63;
        int c = cw_of(w);
        curb[i] = pack2(x[node * DIM + c], x[node * DIM + c + 16]);
    } else if (b < 12884) {
        int i = (b - 12500) * 256 + t;
        if (i < NLAYER * 2 * DIM * DIM) {
            int p = i & 127, n = (i >> 7) & 127, mat = (i >> 14) & 1, l = i >> 15;
            int c = cw_of(p >> 1) + (p & 1) * 16;
            const float* W = mat ? Wr : Wl;
            Wt[i] = f2b(W[l * DIM * DIM + c * DIM + n]);
        }
    } else if (b < 15384) {
        int e = (b - 12884) * 256 + t;       // e < 640000 exactly
        atomicAdd(&deg[dst[e]], 1);
    } else {
        int i = t;
        if (i < NLAYER * 64) {
            int l = i >> 6, w = i & 63;
            int c = cw_of(w);
            const float* A = att + l * DIM;
            const float* B = bias + l * DIM;
            const float* G = gamma + l * DIM;
            const float* E = beta + l * DIM;
            params[l * 256 + w]       = make_float2(A[c] * LOG2E, A[c + 16] * LOG2E);
            params[l * 256 + 64 + w]  = make_float2(B[c], B[c + 16]);
            params[l * 256 + 128 + w] = make_float2(G[c], G[c + 16]);
            params[l * 256 + 192 + w] = make_float2(E[c], E[c + 16]);
        }
    }
}

// ---------------- CSR build + contention-free counting sort ----------------

__global__ __launch_bounds__(1024) void scan1(const int* __restrict__ deg,
                                              int* __restrict__ rowptr,
                                              int* __restrict__ bsum,
                                              int* __restrict__ blockhist) {
    __shared__ int sd[1024];
    __shared__ int lh[256];
    int t = threadIdx.x;
    int idx = blockIdx.x * 1024 + t;
    if (t < 256) lh[t] = 0;
    __syncthreads();
    int v = (idx < N_NODES) ? deg[idx] : 0;
    if (idx < N_NODES) atomicAdd(&lh[v < 255 ? v : 255], 1);
    sd[t] = v;
    __syncthreads();
    for (int off = 1; off < 1024; off <<= 1) {
        int add = (t >= off) ? sd[t - off] : 0;
        __syncthreads();
        sd[t] += add;
        __syncthreads();
    }
    if (idx < N_NODES) rowptr[idx + 1] = sd[t];
    if (t == 1023) bsum[blockIdx.x] = sd[1023];
    if (t < 256) blockhist[blockIdx.x * 256 + t] = lh[t];
}

__global__ __launch_bounds__(1024) void midscan(const int* __restrict__ bsum,
                                                int* __restrict__ bcarry,
                                                const int* __restrict__ blockhist,
                                                int* __restrict__ bboff) {
    __shared__ int sh[256];
    int t = threadIdx.x;
    if (t < 256) {
        int tot = 0;
        for (int b = 0; b < NSCAN; ++b) tot += blockhist[b * 256 + t];
        sh[t] = tot;
    }
    __syncthreads();
    for (int off = 1; off < 256; off <<= 1) {
        int add = 0;
        if (t < 256 && t >= off) add = sh[t - off];
        __syncthreads();
        if (t < 256) sh[t] += add;
        __syncthreads();
    }
    if (t < 256) {
        int run = sh[255] - sh[t];          // heavy-first
        for (int b = 0; b < NSCAN; ++b) {
            bboff[b * 256 + t] = run;
            run += blockhist[b * 256 + t];
        }
    }
    if (t == 0) {
        int c = 0;
        for (int b = 0; b < NSCAN; ++b) { bcarry[b] = c; c += bsum[b]; }
    }
}

__global__ __launch_bounds__(1024) void scan2(int* __restrict__ rowptr,
                                              const int* __restrict__ bcarry,
                                              const int* __restrict__ deg,
                                              const int* __restrict__ bboff,
                                              int* __restrict__ order) {
    __shared__ int lh[256];
    int t = threadIdx.x;
    int idx = blockIdx.x * 1024 + t;
    if (t < 256) lh[t] = 0;
    __syncthreads();
    int carry = bcarry[blockIdx.x];
    if (idx == 0) rowptr[0] = 0;
    if (idx < N_NODES) {
        rowptr[idx + 1] += carry;
        int d = deg[idx];
        int bin = d < 255 ? d : 255;
        int rank = atomicAdd(&lh[bin], 1);
        order[bboff[blockIdx.x * 256 + bin] + rank] = idx;
    }
}

// ---------------- merged GEMM (+ optional scatter) ----------------
// do_scat: blocks [0,SCATB) run the edge scatter; the rest run the MFMA GEMM.
// GEMM pipelines K in 4 slices with double-buffered fragments.

__global__ __launch_bounds__(256) void gemm_sc(
    const ushort* __restrict__ A,      // [N][128] bf16, k-permuted packed order
    const ushort* __restrict__ Wt_l,   // [2][128n][128kperm] bf16
    const float* __restrict__ bl, const float* __restrict__ br,
    unsigned* __restrict__ xlb, unsigned* __restrict__ xrb,
    int do_scat,
    const int* __restrict__ src, const int* __restrict__ dst,
    const int* __restrict__ rowptr, int* __restrict__ cnt,
    int* __restrict__ esrc,
    const int* __restrict__ order, const int* __restrict__ deg,
    int4* __restrict__ slotinfo)
{
    int b = blockIdx.x, t = threadIdx.x;
    if (do_scat) {
        if (b < SCATB) {
            int e = b * 256 + t;             // e < 640000 exactly
            int d = dst[e];
            int pos = rowptr[d] + atomicAdd(&cnt[d], 1);
            esrc[pos] = src[e] << 8;
            if (e < N_NODES) {
                int nd = order[e];
                int r0 = rowptr[nd];
                slotinfo[e] = make_int4(nd, r0, r0 + deg[nd], 0);
            }
            return;
        }
        b -= SCATB;
    }

    int mat = b >= NG;
    int rowbase = (mat ? b - NG : b) * 128;
    int wid = t >> 6;
    int lane = t & 63;
    int wr = wid >> 1, wc = wid & 1;
    int m0 = rowbase + wr * 64, n0 = wc * 64;

    const ushort* W = Wt_l + mat * DIM * DIM;
    const float* bias = mat ? br : bl;
    unsigned* out = mat ? xrb : xlb;

    int fr = lane & 15;
    int kg = lane >> 4;

    const ushort* pa[4];
    #pragma unroll
    for (int mf = 0; mf < 4; ++mf) {
        int row = m0 + mf * 16 + fr;
        if (row > N_NODES - 1) row = N_NODES - 1;
        pa[mf] = A + (size_t)row * DIM + kg * 8;
    }
    const ushort* pb[4];
    #pragma unroll
    for (int nf = 0; nf < 4; ++nf)
        pb[nf] = W + (size_t)(n0 + nf * 16 + fr) * DIM + kg * 8;

    bf16x8 af[2][4], bfr[2][4];
    #pragma unroll
    for (int mf = 0; mf < 4; ++mf) af[0][mf] = *reinterpret_cast<const bf16x8*>(pa[mf]);
    #pragma unroll
    for (int nf = 0; nf < 4; ++nf) bfr[0][nf] = *reinterpret_cast<const bf16x8*>(pb[nf]);

    f32x4 acc[4][4];
    #pragma unroll
    for (int mf = 0; mf < 4; ++mf)
        #pragma unroll
        for (int nf = 0; nf < 4; ++nf)
            acc[mf][nf] = (f32x4){0.f, 0.f, 0.f, 0.f};

    #pragma unroll
    for (int kf = 0; kf < 4; ++kf) {
        int cur = kf & 1, nxt = cur ^ 1;
        if (kf < 3) {
            #pragma unroll
            for (int mf = 0; mf < 4; ++mf)
                af[nxt][mf] = *reinterpret_cast<const bf16x8*>(pa[mf] + (kf + 1) * 32);
            #pragma unroll
            for (int nf = 0; nf < 4; ++nf)
                bfr[nxt][nf] = *reinterpret_cast<const bf16x8*>(pb[nf] + (kf + 1) * 32);
        }
        #pragma unroll
        for (int mf = 0; mf < 4; ++mf)
            #pragma unroll
            for (int nf = 0; nf < 4; ++nf)
                acc[mf][nf] = __builtin_amdgcn_mfma_f32_16x16x32_bf16(
                    af[cur][mf], bfr[cur][nf], acc[mf][nf], 0, 0, 0);
    }

    int col = lane & 15;
    int r4 = lane >> 4;
    float bb[4];
    #pragma unroll
    for (int nf = 0; nf < 4; ++nf) bb[nf] = bias[n0 + nf * 16 + col];

    #pragma unroll
    for (int mf = 0; mf < 4; ++mf) {
        #pragma unroll
        for (int pj = 0; pj < 2; ++pj) {
            // channels c = 64*wc + 32*pj + col, c+16 -> word w = col + 32*wc + 16*pj
            int w = col + 32 * wc + 16 * pj;
            #pragma unroll
            for (int r = 0; r < 4; ++r) {
                int row = m0 + mf * 16 + r4 * 4 + r;
                if (row < N_NODES)
                    out[(size_t)row * 64 + w] =
                        pack2(acc[mf][2 * pj][r] + bb[2 * pj],
                              acc[mf][2 * pj + 1][r] + bb[2 * pj + 1]);
            }
        }
    }
}

// ---------------- fused aggregation (r8 structure + slotinfo + hoisted epilogue) ----

__device__ inline void gather8(const char* __restrict__ xb, int laneoff,
                               const int j[8], unsigned u[8]) {
    #pragma unroll
    for (int i = 0; i < 8; ++i)
        u[i] = *(const unsigned*)(xb + j[i] + laneoff);
}

__device__ inline void compute8(const unsigned u[8], float ax, float ay,
                                float xrx, float xry,
                                float& s, float& ox, float& oy) {
    #pragma unroll
    for (int i = 0; i < 8; ++i) {
        float vx = bf_lo(u[i]), vy = bf_hi(u[i]);
        float p = lr(vx + xrx) * ax + lr(vy + xry) * ay;
        p = reduce16(p);
        float w = EXP2(p);
        s += w; ox = fmaf(w, vx, ox); oy = fmaf(w, vy, oy);
    }
}

__device__ inline void computeT(const unsigned u[8], float ax, float ay,
                                float xrx, float xry,
                                float& s, float& ox, float& oy, int rem) {
    #pragma unroll
    for (int i = 0; i < 8; ++i) {
        if (i < rem) {     // wave-uniform predicate
            float vx = bf_lo(u[i]), vy = bf_hi(u[i]);
            float p = lr(vx + xrx) * ax + lr(vy + xry) * ay;
            p = reduce16(p);
            float w = EXP2(p);
            s += w; ox = fmaf(w, vx, ox); oy = fmaf(w, vy, oy);
        }
    }
}

__global__ __launch_bounds__(256) void agg_kernel(
    const unsigned* __restrict__ xlb2, const unsigned* __restrict__ xrb2,
    const int* __restrict__ esrc, const int4* __restrict__ slotinfo,
    const float2* __restrict__ P4,
    unsigned* __restrict__ curb, float* __restrict__ outf, int last)
{
    int slot = blockIdx.x * 4 + (threadIdx.x >> 6);
    int lane = threadIdx.x & 63;
    int4 si = slotinfo[slot];
    int node = __builtin_amdgcn_readfirstlane(si.x);
    int e0   = __builtin_amdgcn_readfirstlane(si.y);
    int e1   = __builtin_amdgcn_readfirstlane(si.z);

    // hoisted loads: hide their latency under the edge loop
    unsigned xru = xrb2[node * 64 + lane];
    float2 att2 = P4[lane];
    float2 b2   = P4[64 + lane];
    float2 g2   = P4[128 + lane];
    float2 be2  = P4[192 + lane];
    unsigned old = curb[node * 64 + lane];
    float xrx = bf_lo(xru), xry = bf_hi(xru);

    const char* xb = (const char*)xlb2;
    int laneoff = lane << 2;

    float s = 0.f, ox = 0.f, oy = 0.f;
    int nb = (e1 - e0) >> 3;
    int rem = (e1 - e0) & 7;

    int jc[8], jn[8];
    unsigned uc[8], un[8];

    if (nb > 0) {
        #pragma unroll
        for (int i = 0; i < 8; ++i) jc[i] = esrc[e0 + i];   // uniform -> s_load
        gather8(xb, laneoff, jc, uc);
    }
    int ec = e0;
    for (int b = 1; b < nb; ++b) {
        int en = ec + 8;
        #pragma unroll
        for (int i = 0; i < 8; ++i) jn[i] = esrc[en + i];
        gather8(xb, laneoff, jn, un);          // next batch in flight
        compute8(uc, att2.x, att2.y, xrx, xry, s, ox, oy);
        #pragma unroll
        for (int i = 0; i < 8; ++i) uc[i] = un[i];
        ec = en;
    }
    if (nb > 0) {
        if (rem) {
            int et = ec + 8;
            #pragma unroll
            for (int i = 0; i < 8; ++i)
                jn[i] = esrc[et + (i < rem ? i : rem - 1)];
            gather8(xb, laneoff, jn, un);      // tail in flight
            compute8(uc, att2.x, att2.y, xrx, xry, s, ox, oy);
            computeT(un, att2.x, att2.y, xrx, xry, s, ox, oy, rem);
        } else {
            compute8(uc, att2.x, att2.y, xrx, xry, s, ox, oy);
        }
    } else if (rem) {
        #pragma unroll
        for (int i = 0; i < 8; ++i)
            jc[i] = esrc[e0 + (i < rem ? i : rem - 1)];
        gather8(xb, laneoff, jc, uc);
        computeT(uc, att2.x, att2.y, xrx, xry, s, ox, oy, rem);
    }

    float inv = 1.f / (s + 1e-16f);
    float gx = fmaxf(fmaf(ox, inv, b2.x), 0.f);
    float gy = fmaxf(fmaf(oy, inv, b2.y), 0.f);

    // LayerNorm over 128 channels
    float sum = gx + gy;
    sum = reduce16(sum);
    sum += __shfl_xor(sum, 16);
    sum += __shfl_xor(sum, 32);
    float mu = sum * (1.f / 128.f);
    float dx = gx - mu, dy = gy - mu;
    float ss = dx * dx + dy * dy;
    ss = reduce16(ss);
    ss += __shfl_xor(ss, 16);
    ss += __shfl_xor(ss, 32);
    float rstd = rsqrtf(ss * (1.f / 128.f) + LN_EPS);

    float yx = fmaf(dx * rstd, g2.x, be2.x) + bf_lo(old);
    float yy = fmaf(dy * rstd, g2.y, be2.y) + bf_hi(old);

    if (last) {
        int c = cw_of(lane);
        outf[node * DIM + c] = yx;
        outf[node * DIM + c + 16] = yy;
    } else {
        curb[node * 64 + lane] = pack2(yx, yy);
    }
}

// ---------------- launch ----------------

extern "C" void kernel_launch(void* const* d_in, const int* in_sizes, int n_in,
                              void* d_out, int out_size, void* d_ws, size_t ws_size,
                              hipStream_t stream) {
    const float* x     = (const float*)d_in[0];
    const int*   ei    = (const int*)d_in[1];
    const float* Wl    = (const float*)d_in[2];
    const float* bl    = (const float*)d_in[3];
    const float* Wr    = (const float*)d_in[4];
    const float* br    = (const float*)d_in[5];
    const float* att   = (const float*)d_in[6];
    const float* bias  = (const float*)d_in[7];
    const float* gamma = (const float*)d_in[8];
    const float* beta  = (const float*)d_in[9];
    float* outf = (float*)d_out;

    char* ws = (char*)d_ws;
    size_t off = 0;
    auto alloc = [&](size_t bytes) -> void* {
        void* p = ws + off;
        off += (bytes + 255) & ~size_t(255);
        return p;
    };
    unsigned* curb = (unsigned*)alloc((size_t)N_NODES * 64 * 4);
    unsigned* xlb  = (unsigned*)alloc((size_t)N_NODES * 64 * 4);
    unsigned* xrb  = (unsigned*)alloc((size_t)N_NODES * 64 * 4);
    ushort* Wt     = (ushort*)alloc((size_t)NLAYER * 2 * DIM * DIM * 2);
    int* esrc      = (int*)alloc((size_t)N_EDGES * 4);
    int* rowptr    = (int*)alloc((size_t)(N_NODES + 1) * 4);
    // contiguous zero region: deg, cnt, bsum, bcarry
    int* zbase     = (int*)alloc((size_t)(2 * N_NODES + 2 * 64) * 4);
    int* deg = zbase, *cnt = zbase + N_NODES;
    int* bsum = cnt + N_NODES, *bcarry = bsum + 64;
    int* blockhist = (int*)alloc((size_t)NSCAN * 256 * 4);
    int* bboff     = (int*)alloc((size_t)NSCAN * 256 * 4);
    int* order     = (int*)alloc((size_t)N_NODES * 4);
    int4* slotinfo = (int4*)alloc((size_t)N_NODES * 16);
    float2* params = (float2*)alloc((size_t)NLAYER * 256 * sizeof(float2));

    const int* srcArr = ei;
    const int* dstArr = ei + N_EDGES;

    int n4 = (2 * N_NODES + 2 * 64) / 4;
    zerofill<<<(n4 + 255) / 256, 256, 0, stream>>>((int4*)zbase, n4);
    fusedinit<<<15385, 256, 0, stream>>>(x, curb, Wl, Wr, Wt, dstArr, deg,
                                         att, bias, gamma, beta, params);
    scan1<<<NSCAN, 1024, 0, stream>>>(deg, rowptr, bsum, blockhist);
    midscan<<<1, 1024, 0, stream>>>(bsum, bcarry, blockhist, bboff);
    scan2<<<NSCAN, 1024, 0, stream>>>(rowptr, bcarry, deg, bboff, order);

    for (int l = 0; l < NLAYER; ++l) {
        int do_scat = (l == 0) ? 1 : 0;
        int grid = 2 * NG + (do_scat ? SCATB : 0);
        gemm_sc<<<grid, 256, 0, stream>>>(
            (const ushort*)curb, Wt + (size_t)l * 2 * DIM * DIM,
            bl + (size_t)l * DIM, br + (size_t)l * DIM, xlb, xrb,
            do_scat, srcArr, dstArr, rowptr, cnt, esrc, order, deg, slotinfo);
        agg_kernel<<<12500, 256, 0, stream>>>(
            xlb, xrb, esrc, slotinfo, params + (size_t)l * 256,
            curb, outf, l == NLAYER - 1 ? 1 : 0);
    }
}

// Round 13
// 229.864 us; speedup vs baseline: 1.9002x; 1.1504x over previous
//
#include <hip/hip_runtime.h>
#include <hip/hip_bf16.h>
#include <math.h>

#define N_NODES 50000
#define N_EDGES 640000
#define DIM 128
#define NLAYER 3
#define LN_EPS 1e-5f
#define LOG2E 1.44269504088896f
#define NSCAN 49    // ceil(50000/1024)
#define NG 391      // ceil(50000/128) row-blocks per matrix
#define SCATB 2500  // scatter blocks (640000/256)

#if __has_builtin(__builtin_amdgcn_exp2f)
#define EXP2(x) __builtin_amdgcn_exp2f(x)
#else
#define EXP2(x) exp2f(x)
#endif

typedef __attribute__((ext_vector_type(8))) short bf16x8;
typedef __attribute__((ext_vector_type(4))) float f32x4;

__device__ inline ushort f2b(float f) {
    __hip_bfloat16 h = __float2bfloat16(f);
    return *reinterpret_cast<ushort*>(&h);
}
__device__ inline float bf_lo(unsigned u) { return __uint_as_float(u << 16); }
__device__ inline float bf_hi(unsigned u) { return __uint_as_float(u & 0xffff0000u); }
// leaky_relu(t) = 0.6t + 0.4|t|  (NEG_SLOPE=0.2)
__device__ inline float lr(float t) { return fmaf(0.4f, fabsf(t), 0.6f * t); }
__device__ inline unsigned pack2(float a, float b) {
    return (unsigned)f2b(a) | ((unsigned)f2b(b) << 16);
}
// packed word w of a node row holds channels (cw, cw+16); both in same head.
__device__ inline int cw_of(int w) { return (w & 15) + 32 * (w >> 4); }

// DPP-based add of cross-lane neighbor (VALU, no LDS pipe).
template<int CTRL>
__device__ inline float dppadd(float v) {
    int m = __builtin_amdgcn_update_dpp(0, __float_as_int(v), CTRL, 0xF, 0xF, true);
    return v + __int_as_float(m);
}
// sum over each 16-lane group
__device__ inline float reduce16(float v) {
    v = dppadd<0x124>(v);   // row_ror:4
    v = dppadd<0x128>(v);   // row_ror:8
    v = dppadd<0xB1>(v);    // quad_perm [1,0,3,2]
    v = dppadd<0x4E>(v);    // quad_perm [2,3,0,1]
    return v;
}

// ---------------- zero-fill ----------------

__global__ __launch_bounds__(256) void zerofill(int4* __restrict__ p, int n4) {
    int i = blockIdx.x * 256 + threadIdx.x;
    if (i < n4) p[i] = make_int4(0, 0, 0, 0);
}

// ---------------- fused init: curb pack + Wt convert(k-perm) + deg hist + params ----

__global__ __launch_bounds__(256) void fusedinit(
    const float* __restrict__ x, unsigned* __restrict__ curb,
    const float* __restrict__ Wl, const float* __restrict__ Wr, ushort* __restrict__ Wt,
    const int* __restrict__ dst, int* __restrict__ deg,
    const float* __restrict__ att, const float* __restrict__ bias,
    const float* __restrict__ gamma, const float* __restrict__ beta,
    float2* __restrict__ params)
{
    int b = blockIdx.x, t = threadIdx.x;
    if (b < 12500) {
        int i = b * 256 + t;                 // i < N*64
        int node = i >> 6, w = i & 63;
        int c = cw_of(w);
        curb[i] = pack2(x[node * DIM + c], x[node * DIM + c + 16]);
    } else if (b < 12884) {
        int i = (b - 12500) * 256 + t;
        if (i < NLAYER * 2 * DIM * DIM) {
            int p = i & 127, n = (i >> 7) & 127, mat = (i >> 14) & 1, l = i >> 15;
            int c = cw_of(p >> 1) + (p & 1) * 16;
            const float* W = mat ? Wr : Wl;
            Wt[i] = f2b(W[l * DIM * DIM + c * DIM + n]);
        }
    } else if (b < 15384) {
        int e = (b - 12884) * 256 + t;       // e < 640000 exactly
        atomicAdd(&deg[dst[e]], 1);
    } else {
        int i = t;
        if (i < NLAYER * 64) {
            int l = i >> 6, w = i & 63;
            int c = cw_of(w);
            const float* A = att + l * DIM;
            const float* B = bias + l * DIM;
            const float* G = gamma + l * DIM;
            const float* E = beta + l * DIM;
            params[l * 256 + w]       = make_float2(A[c] * LOG2E, A[c + 16] * LOG2E);
            params[l * 256 + 64 + w]  = make_float2(B[c], B[c + 16]);
            params[l * 256 + 128 + w] = make_float2(G[c], G[c + 16]);
            params[l * 256 + 192 + w] = make_float2(E[c], E[c + 16]);
        }
    }
}

// ---------------- CSR build + contention-free counting sort ----------------

__global__ __launch_bounds__(1024) void scan1(const int* __restrict__ deg,
                                              int* __restrict__ rowptr,
                                              int* __restrict__ bsum,
                                              int* __restrict__ blockhist) {
    __shared__ int sd[1024];
    __shared__ int lh[256];
    int t = threadIdx.x;
    int idx = blockIdx.x * 1024 + t;
    if (t < 256) lh[t] = 0;
    __syncthreads();
    int v = (idx < N_NODES) ? deg[idx] : 0;
    if (idx < N_NODES) atomicAdd(&lh[v < 255 ? v : 255], 1);
    sd[t] = v;
    __syncthreads();
    for (int off = 1; off < 1024; off <<= 1) {
        int add = (t >= off) ? sd[t - off] : 0;
        __syncthreads();
        sd[t] += add;
        __syncthreads();
    }
    if (idx < N_NODES) rowptr[idx + 1] = sd[t];
    if (t == 1023) bsum[blockIdx.x] = sd[1023];
    if (t < 256) blockhist[blockIdx.x * 256 + t] = lh[t];
}

__global__ __launch_bounds__(1024) void midscan(const int* __restrict__ bsum,
                                                int* __restrict__ bcarry,
                                                const int* __restrict__ blockhist,
                                                int* __restrict__ bboff) {
    __shared__ int sh[256];
    int t = threadIdx.x;
    if (t < 256) {
        int tot = 0;
        for (int b = 0; b < NSCAN; ++b) tot += blockhist[b * 256 + t];
        sh[t] = tot;
    }
    __syncthreads();
    for (int off = 1; off < 256; off <<= 1) {
        int add = 0;
        if (t < 256 && t >= off) add = sh[t - off];
        __syncthreads();
        if (t < 256) sh[t] += add;
        __syncthreads();
    }
    if (t < 256) {
        int run = sh[255] - sh[t];          // heavy-first
        for (int b = 0; b < NSCAN; ++b) {
            bboff[b * 256 + t] = run;
            run += blockhist[b * 256 + t];
        }
    }
    if (t == 0) {
        int c = 0;
        for (int b = 0; b < NSCAN; ++b) { bcarry[b] = c; c += bsum[b]; }
    }
}

__global__ __launch_bounds__(1024) void scan2(int* __restrict__ rowptr,
                                              const int* __restrict__ bcarry,
                                              const int* __restrict__ deg,
                                              const int* __restrict__ bboff,
                                              int* __restrict__ order) {
    __shared__ int lh[256];
    int t = threadIdx.x;
    int idx = blockIdx.x * 1024 + t;
    if (t < 256) lh[t] = 0;
    __syncthreads();
    int carry = bcarry[blockIdx.x];
    if (idx == 0) rowptr[0] = 0;
    if (idx < N_NODES) {
        rowptr[idx + 1] += carry;
        int d = deg[idx];
        int bin = d < 255 ? d : 255;
        int rank = atomicAdd(&lh[bin], 1);
        order[bboff[blockIdx.x * 256 + bin] + rank] = idx;
    }
}

// ---------------- LDS-staged MFMA GEMM (+ optional merged scatter) ----------------
// Tile: 128 rows x 128 cols, K=128 in one shot. A/B staged in LDS with
// chunk-XOR swizzle (conflict-free ds_read_b128); output repacked through LDS
// for full-line dwordx4 stores.

__global__ __launch_bounds__(256) void gemm_sc(
    const ushort* __restrict__ A,      // [N][128] bf16, k-permuted packed order
    const ushort* __restrict__ Wt_l,   // [2][128n][128kperm] bf16
    const float* __restrict__ bl, const float* __restrict__ br,
    unsigned* __restrict__ xlb, unsigned* __restrict__ xrb,
    int do_scat,
    const int* __restrict__ src, const int* __restrict__ dst,
    const int* __restrict__ rowptr, int* __restrict__ cnt,
    int* __restrict__ esrc,
    const int* __restrict__ order, const int* __restrict__ deg,
    int4* __restrict__ slotinfo)
{
    __shared__ char ldsA[32768];
    __shared__ char ldsB[32768];
    int b = blockIdx.x, t = threadIdx.x;
    if (do_scat) {
        if (b < SCATB) {
            int e = b * 256 + t;             // e < 640000 exactly
            int d = dst[e];
            int pos = rowptr[d] + atomicAdd(&cnt[d], 1);
            esrc[pos] = src[e] << 8;
            if (e < N_NODES) {
                int nd = order[e];
                int r0 = rowptr[nd];
                slotinfo[e] = make_int4(nd, r0, r0 + deg[nd], 0);
            }
            return;
        }
        b -= SCATB;
    }

    int mat = b >= NG;
    int rowbase = (mat ? b - NG : b) * 128;

    // ---- stage A-tile (contiguous 32KB) and B-tile, swizzled chunk placement
    const char* Ab = (const char*)A + (size_t)rowbase * 256;
    const char* Bb = (const char*)(Wt_l + (size_t)mat * DIM * DIM);
    #pragma unroll
    for (int i = 0; i < 8; ++i) {
        int o = (i * 256 + t) * 16;              // linear byte offset in tile
        int row = o >> 8, ch = (o >> 4) & 15;
        int sw = row * 256 + ((ch ^ (row & 7)) << 4);
        *(uint4*)&ldsA[sw] = *(const uint4*)(Ab + o);   // coalesced full-line reads
        *(uint4*)&ldsB[sw] = *(const uint4*)(Bb + o);
    }
    __syncthreads();

    int wid = t >> 6, lane = t & 63;
    int wr = wid >> 1, wc = wid & 1;
    int fr = lane & 15, kg = lane >> 4;

    f32x4 acc[4][4];
    #pragma unroll
    for (int mf = 0; mf < 4; ++mf)
        #pragma unroll
        for (int nf = 0; nf < 4; ++nf)
            acc[mf][nf] = (f32x4){0.f, 0.f, 0.f, 0.f};

    #pragma unroll
    for (int kf = 0; kf < 4; ++kf) {
        int c = kf * 4 + kg;
        bf16x8 af[4], bfr[4];
        #pragma unroll
        for (int mf = 0; mf < 4; ++mf) {
            int rl = wr * 64 + mf * 16 + fr;
            af[mf] = *(const bf16x8*)&ldsA[rl * 256 + ((c ^ (rl & 7)) << 4)];
        }
        #pragma unroll
        for (int nf = 0; nf < 4; ++nf) {
            int nl = wc * 64 + nf * 16 + fr;
            bfr[nf] = *(const bf16x8*)&ldsB[nl * 256 + ((c ^ (nl & 7)) << 4)];
        }
        #pragma unroll
        for (int mf = 0; mf < 4; ++mf)
            #pragma unroll
            for (int nf = 0; nf < 4; ++nf)
                acc[mf][nf] = __builtin_amdgcn_mfma_f32_16x16x32_bf16(
                    af[mf], bfr[nf], acc[mf][nf], 0, 0, 0);
    }
    __syncthreads();    // done reading ldsA -> reuse as output tile

    const float* bias = mat ? br : bl;
    int col = fr;
    int r4 = kg;
    float bb[4];
    #pragma unroll
    for (int nf = 0; nf < 4; ++nf) bb[nf] = bias[wc * 64 + nf * 16 + col];

    unsigned* ldsO = (unsigned*)ldsA;
    #pragma unroll
    for (int mf = 0; mf < 4; ++mf) {
        #pragma unroll
        for (int pj = 0; pj < 2; ++pj) {
            // channels c = 64*wc + 32*pj + col, c+16 -> word w = col + 32*wc + 16*pj
            int w = col + 32 * wc + 16 * pj;
            #pragma unroll
            for (int r = 0; r < 4; ++r) {
                int rl = wr * 64 + mf * 16 + r4 * 4 + r;
                ldsO[rl * 64 + w] =
                    pack2(acc[mf][2 * pj][r] + bb[2 * pj],
                          acc[mf][2 * pj + 1][r] + bb[2 * pj + 1]);
            }
        }
    }
    __syncthreads();

    // ---- coalesced full-line output
    unsigned* out = mat ? xrb : xlb;
    char* ob = (char*)out + (size_t)rowbase * 256;
    #pragma unroll
    for (int i = 0; i < 8; ++i) {
        int o = (i * 256 + t) * 16;
        int row = rowbase + (o >> 8);
        if (row < N_NODES)
            *(uint4*)(ob + o) = *(const uint4*)&ldsA[o];
    }
}

// ---------------- fused aggregation (r8 structure + slotinfo + hoisted epilogue) ----

__device__ inline void gather8(const char* __restrict__ xb, int laneoff,
                               const int j[8], unsigned u[8]) {
    #pragma unroll
    for (int i = 0; i < 8; ++i)
        u[i] = *(const unsigned*)(xb + j[i] + laneoff);
}

__device__ inline void compute8(const unsigned u[8], float ax, float ay,
                                float xrx, float xry,
                                float& s, float& ox, float& oy) {
    #pragma unroll
    for (int i = 0; i < 8; ++i) {
        float vx = bf_lo(u[i]), vy = bf_hi(u[i]);
        float p = lr(vx + xrx) * ax + lr(vy + xry) * ay;
        p = reduce16(p);
        float w = EXP2(p);
        s += w; ox = fmaf(w, vx, ox); oy = fmaf(w, vy, oy);
    }
}

__device__ inline void computeT(const unsigned u[8], float ax, float ay,
                                float xrx, float xry,
                                float& s, float& ox, float& oy, int rem) {
    #pragma unroll
    for (int i = 0; i < 8; ++i) {
        if (i < rem) {     // wave-uniform predicate
            float vx = bf_lo(u[i]), vy = bf_hi(u[i]);
            float p = lr(vx + xrx) * ax + lr(vy + xry) * ay;
            p = reduce16(p);
            float w = EXP2(p);
            s += w; ox = fmaf(w, vx, ox); oy = fmaf(w, vy, oy);
        }
    }
}

__global__ __launch_bounds__(256) void agg_kernel(
    const unsigned* __restrict__ xlb2, const unsigned* __restrict__ xrb2,
    const int* __restrict__ esrc, const int4* __restrict__ slotinfo,
    const float2* __restrict__ P4,
    unsigned* __restrict__ curb, float* __restrict__ outf, int last)
{
    int slot = blockIdx.x * 4 + (threadIdx.x >> 6);
    int lane = threadIdx.x & 63;
    int4 si = slotinfo[slot];
    int node = __builtin_amdgcn_readfirstlane(si.x);
    int e0   = __builtin_amdgcn_readfirstlane(si.y);
    int e1   = __builtin_amdgcn_readfirstlane(si.z);

    // hoisted loads: hide their latency under the edge loop
    unsigned xru = xrb2[node * 64 + lane];
    float2 att2 = P4[lane];
    float2 b2   = P4[64 + lane];
    float2 g2   = P4[128 + lane];
    float2 be2  = P4[192 + lane];
    unsigned old = curb[node * 64 + lane];
    float xrx = bf_lo(xru), xry = bf_hi(xru);

    const char* xb = (const char*)xlb2;
    int laneoff = lane << 2;

    float s = 0.f, ox = 0.f, oy = 0.f;
    int nb = (e1 - e0) >> 3;
    int rem = (e1 - e0) & 7;

    int jc[8], jn[8];
    unsigned uc[8], un[8];

    if (nb > 0) {
        #pragma unroll
        for (int i = 0; i < 8; ++i) jc[i] = esrc[e0 + i];   // uniform -> s_load
        gather8(xb, laneoff, jc, uc);
    }
    int ec = e0;
    for (int b = 1; b < nb; ++b) {
        int en = ec + 8;
        #pragma unroll
        for (int i = 0; i < 8; ++i) jn[i] = esrc[en + i];
        gather8(xb, laneoff, jn, un);          // next batch in flight
        compute8(uc, att2.x, att2.y, xrx, xry, s, ox, oy);
        #pragma unroll
        for (int i = 0; i < 8; ++i) uc[i] = un[i];
        ec = en;
    }
    if (nb > 0) {
        if (rem) {
            int et = ec + 8;
            #pragma unroll
            for (int i = 0; i < 8; ++i)
                jn[i] = esrc[et + (i < rem ? i : rem - 1)];
            gather8(xb, laneoff, jn, un);      // tail in flight
            compute8(uc, att2.x, att2.y, xrx, xry, s, ox, oy);
            computeT(un, att2.x, att2.y, xrx, xry, s, ox, oy, rem);
        } else {
            compute8(uc, att2.x, att2.y, xrx, xry, s, ox, oy);
        }
    } else if (rem) {
        #pragma unroll
        for (int i = 0; i < 8; ++i)
            jc[i] = esrc[e0 + (i < rem ? i : rem - 1)];
        gather8(xb, laneoff, jc, uc);
        computeT(uc, att2.x, att2.y, xrx, xry, s, ox, oy, rem);
    }

    float inv = 1.f / (s + 1e-16f);
    float gx = fmaxf(fmaf(ox, inv, b2.x), 0.f);
    float gy = fmaxf(fmaf(oy, inv, b2.y), 0.f);

    // LayerNorm over 128 channels
    float sum = gx + gy;
    sum = reduce16(sum);
    sum += __shfl_xor(sum, 16);
    sum += __shfl_xor(sum, 32);
    float mu = sum * (1.f / 128.f);
    float dx = gx - mu, dy = gy - mu;
    float ss = dx * dx + dy * dy;
    ss = reduce16(ss);
    ss += __shfl_xor(ss, 16);
    ss += __shfl_xor(ss, 32);
    float rstd = rsqrtf(ss * (1.f / 128.f) + LN_EPS);

    float yx = fmaf(dx * rstd, g2.x, be2.x) + bf_lo(old);
    float yy = fmaf(dy * rstd, g2.y, be2.y) + bf_hi(old);

    if (last) {
        int c = cw_of(lane);
        outf[node * DIM + c] = yx;
        outf[node * DIM + c + 16] = yy;
    } else {
        curb[node * 64 + lane] = pack2(yx, yy);
    }
}

// ---------------- launch ----------------

extern "C" void kernel_launch(void* const* d_in, const int* in_sizes, int n_in,
                              void* d_out, int out_size, void* d_ws, size_t ws_size,
                              hipStream_t stream) {
    const float* x     = (const float*)d_in[0];
    const int*   ei    = (const int*)d_in[1];
    const float* Wl    = (const float*)d_in[2];
    const float* bl    = (const float*)d_in[3];
    const float* Wr    = (const float*)d_in[4];
    const float* br    = (const float*)d_in[5];
    const float* att   = (const float*)d_in[6];
    const float* bias  = (const float*)d_in[7];
    const float* gamma = (const float*)d_in[8];
    const float* beta  = (const float*)d_in[9];
    float* outf = (float*)d_out;

    char* ws = (char*)d_ws;
    size_t off = 0;
    auto alloc = [&](size_t bytes) -> void* {
        void* p = ws + off;
        off += (bytes + 255) & ~size_t(255);
        return p;
    };
    unsigned* curb = (unsigned*)alloc((size_t)N_NODES * 64 * 4);
    unsigned* xlb  = (unsigned*)alloc((size_t)N_NODES * 64 * 4);
    unsigned* xrb  = (unsigned*)alloc((size_t)N_NODES * 64 * 4);
    ushort* Wt     = (ushort*)alloc((size_t)NLAYER * 2 * DIM * DIM * 2);
    int* esrc      = (int*)alloc((size_t)N_EDGES * 4);
    int* rowptr    = (int*)alloc((size_t)(N_NODES + 1) * 4);
    // contiguous zero region: deg, cnt, bsum, bcarry
    int* zbase     = (int*)alloc((size_t)(2 * N_NODES + 2 * 64) * 4);
    int* deg = zbase, *cnt = zbase + N_NODES;
    int* bsum = cnt + N_NODES, *bcarry = bsum + 64;
    int* blockhist = (int*)alloc((size_t)NSCAN * 256 * 4);
    int* bboff     = (int*)alloc((size_t)NSCAN * 256 * 4);
    int* order     = (int*)alloc((size_t)N_NODES * 4);
    int4* slotinfo = (int4*)alloc((size_t)N_NODES * 16);
    float2* params = (float2*)alloc((size_t)NLAYER * 256 * sizeof(float2));

    const int* srcArr = ei;
    const int* dstArr = ei + N_EDGES;

    int n4 = (2 * N_NODES + 2 * 64) / 4;
    zerofill<<<(n4 + 255) / 256, 256, 0, stream>>>((int4*)zbase, n4);
    fusedinit<<<15385, 256, 0, stream>>>(x, curb, Wl, Wr, Wt, dstArr, deg,
                                         att, bias, gamma, beta, params);
    scan1<<<NSCAN, 1024, 0, stream>>>(deg, rowptr, bsum, blockhist);
    midscan<<<1, 1024, 0, stream>>>(bsum, bcarry, blockhist, bboff);
    scan2<<<NSCAN, 1024, 0, stream>>>(rowptr, bcarry, deg, bboff, order);

    for (int l = 0; l < NLAYER; ++l) {
        int do_scat = (l == 0) ? 1 : 0;
        int grid = 2 * NG + (do_scat ? SCATB : 0);
        gemm_sc<<<grid, 256, 0, stream>>>(
            (const ushort*)curb, Wt + (size_t)l * 2 * DIM * DIM,
            bl + (size_t)l * DIM, br + (size_t)l * DIM, xlb, xrb,
            do_scat, srcArr, dstArr, rowptr, cnt, esrc, order, deg, slotinfo);
        agg_kernel<<<12500, 256, 0, stream>>>(
            xlb, xrb, esrc, slotinfo, params + (size_t)l * 256,
            curb, outf, l == NLAYER - 1 ? 1 : 0);
    }
}